// Round 1
// baseline (2244.404 us; speedup 1.0000x reference)
//
#include <hip/hip_runtime.h>
#include <math.h>

#define NN 10000
#define EE 100000
#define EPE 110000   // edges + self loops
#define CC 200

__device__ __forceinline__ float lrelu(float v) { return v >= 0.f ? v : 0.2f * v; }
__device__ __forceinline__ float gelu_f(float v) { return 0.5f * v * (1.f + erff(v * 0.70710678118654752f)); }

// ---------------- CSR build ----------------

__global__ void build_edges_kernel(const int* __restrict__ ei,
                                   int* __restrict__ src_all, int* __restrict__ dst_all,
                                   int* __restrict__ deg) {
    int e = blockIdx.x * blockDim.x + threadIdx.x;
    if (e >= EPE) return;
    int s, d;
    if (e < EE) { s = ei[e]; d = ei[EE + e]; }
    else        { s = e - EE; d = e - EE; }
    src_all[e] = s;
    dst_all[e] = d;
    atomicAdd(&deg[d], 1);
}

__global__ void scan_kernel(const int* __restrict__ deg, int* __restrict__ row_ptr, int n) {
    __shared__ int sm[1024];
    int tid = threadIdx.x;
    int carry = 0;
    for (int base = 0; base < n; base += 1024) {
        int idx = base + tid;
        int v = (idx < n) ? deg[idx] : 0;
        sm[tid] = v;
        __syncthreads();
        for (int off = 1; off < 1024; off <<= 1) {
            int t = (tid >= off) ? sm[tid - off] : 0;
            __syncthreads();
            sm[tid] += t;
            __syncthreads();
        }
        if (idx < n) row_ptr[idx] = carry + sm[tid] - v;   // exclusive
        carry += sm[1023];
        __syncthreads();
    }
    if (tid == 0) row_ptr[n] = carry;
}

__global__ void scatter_kernel(const int* __restrict__ src_all, const int* __restrict__ dst_all,
                               const int* __restrict__ row_ptr, int* __restrict__ cursor,
                               int* __restrict__ col_src) {
    int e = blockIdx.x * blockDim.x + threadIdx.x;
    if (e >= EPE) return;
    int d = dst_all[e];
    int pos = row_ptr[d] + atomicAdd(&cursor[d], 1);
    col_src[pos] = src_all[e];
}

// ---------------- GEMM (fp32, 64x64x16 tile, 256 thr, 4x4/thread) ----------------

__global__ __launch_bounds__(256) void gemm_kernel(const float* __restrict__ A,
                                                   const float* __restrict__ B,
                                                   float* __restrict__ C,
                                                   int M, int K, int Nc) {
    __shared__ float As[16][65];
    __shared__ float Bs[16][65];
    int tid = threadIdx.x;
    int row0 = blockIdx.y * 64, col0 = blockIdx.x * 64;
    int tx = tid & 15, ty = tid >> 4;
    float acc[4][4] = {};
    int am = tid >> 2, ak = (tid & 3) << 2;
    int bk = tid >> 4, bn = (tid & 15) << 2;
    for (int k0 = 0; k0 < K; k0 += 16) {
        int gm = row0 + am;
#pragma unroll
        for (int q = 0; q < 4; ++q) {
            int gk = k0 + ak + q;
            As[ak + q][am] = (gm < M && gk < K) ? A[gm * K + gk] : 0.f;
        }
        int gk = k0 + bk;
#pragma unroll
        for (int q = 0; q < 4; ++q) {
            int gn = col0 + bn + q;
            Bs[bk][bn + q] = (gk < K && gn < Nc) ? B[gk * Nc + gn] : 0.f;
        }
        __syncthreads();
#pragma unroll
        for (int kk = 0; kk < 16; ++kk) {
            float a[4], b[4];
#pragma unroll
            for (int i = 0; i < 4; ++i) a[i] = As[kk][ty * 4 + i];
#pragma unroll
            for (int j = 0; j < 4; ++j) b[j] = Bs[kk][tx * 4 + j];
#pragma unroll
            for (int i = 0; i < 4; ++i)
#pragma unroll
                for (int j = 0; j < 4; ++j) acc[i][j] += a[i] * b[j];
        }
        __syncthreads();
    }
#pragma unroll
    for (int i = 0; i < 4; ++i) {
        int gm = row0 + ty * 4 + i;
        if (gm >= M) continue;
#pragma unroll
        for (int j = 0; j < 4; ++j) {
            int gn = col0 + tx * 4 + j;
            if (gn < Nc) C[gm * Nc + gn] = acc[i][j];
        }
    }
}

// ---------------- attention scores: asrc/adst = einsum(h, a) ----------------

__global__ void attn_kernel(const float* __restrict__ h,
                            const float* __restrict__ a_s, const float* __restrict__ a_d,
                            float* __restrict__ asrc, float* __restrict__ adst,
                            int H, int HC) {
    int n = blockIdx.x;
    int wave = threadIdx.x >> 6;
    int lane = threadIdx.x & 63;
    if (wave >= H) return;
    float sa = 0.f, da = 0.f;
    const float* hrow = h + (size_t)n * HC + wave * CC;
    for (int c = lane; c < CC; c += 64) {
        float hv = hrow[c];
        sa += hv * a_s[wave * CC + c];
        da += hv * a_d[wave * CC + c];
    }
#pragma unroll
    for (int off = 32; off > 0; off >>= 1) {
        sa += __shfl_down(sa, off);
        da += __shfl_down(da, off);
    }
    if (lane == 0) {
        asrc[n * H + wave] = sa;
        adst[n * H + wave] = da;
    }
}

// ---------------- per-dst segment softmax + aggregation + bias + gelu ----------------

__global__ __launch_bounds__(256) void agg_kernel(const float* __restrict__ h,
                                                  const float* __restrict__ asrc,
                                                  const float* __restrict__ adst,
                                                  const int* __restrict__ row_ptr,
                                                  const int* __restrict__ col_src,
                                                  const float* __restrict__ bias,
                                                  float* __restrict__ out,
                                                  float* __restrict__ m_out,
                                                  float* __restrict__ den_out,
                                                  int H, int HC) {
    int n = blockIdx.x;
    int tid = threadIdx.x;
    __shared__ float w_lds[4];
    __shared__ float m_s[4], den_s[4], ad_s[4];
    int beg = row_ptr[n], end = row_ptr[n + 1];

    if (tid < H) {
        float ad = adst[n * H + tid];
        float mmax = -1e30f;
        for (int e = beg; e < end; ++e) {
            int s = col_src[e];
            float ev = lrelu(asrc[s * H + tid] + ad);
            mmax = fmaxf(mmax, ev);
        }
        float den = 0.f;
        for (int e = beg; e < end; ++e) {
            int s = col_src[e];
            float ev = lrelu(asrc[s * H + tid] + ad);
            den += expf(ev - mmax);
        }
        m_s[tid] = mmax; den_s[tid] = den; ad_s[tid] = ad;
        m_out[n * H + tid] = mmax;
        den_out[n * H + tid] = den;
    }
    __syncthreads();

    float acc[4] = {0.f, 0.f, 0.f, 0.f};
    for (int e = beg; e < end; ++e) {
        int s = col_src[e];
        if (tid < H) {
            float ev = lrelu(asrc[s * H + tid] + ad_s[tid]);
            w_lds[tid] = expf(ev - m_s[tid]) / den_s[tid];
        }
        __syncthreads();
        const float* hrow = h + (size_t)s * HC;
#pragma unroll
        for (int k = 0; k < 4; ++k) {
            int hc = tid + k * 256;
            if (hc < HC) acc[k] += w_lds[hc / CC] * hrow[hc];
        }
        __syncthreads();
    }
#pragma unroll
    for (int k = 0; k < 4; ++k) {
        int hc = tid + k * 256;
        if (hc < HC) out[(size_t)n * HC + hc] = gelu_f(acc[k] + bias[hc]);
    }
}

// ---------------- layer-4 edge attention output (original edge order) ----------------

__global__ void alpha_kernel(const int* __restrict__ src_all, const int* __restrict__ dst_all,
                             const float* __restrict__ asrc, const float* __restrict__ adst,
                             const float* __restrict__ m, const float* __restrict__ den,
                             float* __restrict__ out_alpha) {
    int e = blockIdx.x * blockDim.x + threadIdx.x;
    if (e >= EPE) return;
    int s = src_all[e], d = dst_all[e];
    float ev = lrelu(asrc[s] + adst[d]);
    out_alpha[e] = expf(ev - m[d]) / den[d];
}

// ---------------- host ----------------

extern "C" void kernel_launch(void* const* d_in, const int* in_sizes, int n_in,
                              void* d_out, int out_size, void* d_ws, size_t ws_size,
                              hipStream_t stream) {
    const float* X = (const float*)d_in[0];
    const int* ei = (const int*)d_in[1];

    char* ws = (char*)d_ws;
    size_t off = 0;
    auto alloc = [&](size_t bytes) { void* p = ws + off; off += (bytes + 255) & ~(size_t)255; return p; };

    float* bufA   = (float*)alloc((size_t)NN * 800 * 4);
    float* bufB   = (float*)alloc((size_t)NN * 800 * 4);
    float* asrc   = (float*)alloc((size_t)NN * 4 * 4);
    float* adst   = (float*)alloc((size_t)NN * 4 * 4);
    float* m_arr  = (float*)alloc((size_t)NN * 4 * 4);
    float* den_arr= (float*)alloc((size_t)NN * 4 * 4);
    int* src_all  = (int*)alloc((size_t)EPE * 4);
    int* dst_all  = (int*)alloc((size_t)EPE * 4);
    int* col_src  = (int*)alloc((size_t)EPE * 4);
    int* row_ptr  = (int*)alloc((size_t)(NN + 1) * 4);
    int* deg      = (int*)alloc((size_t)NN * 4);
    int* cursor   = (int*)alloc((size_t)NN * 4);

    hipMemsetAsync(deg, 0, NN * sizeof(int), stream);
    hipMemsetAsync(cursor, 0, NN * sizeof(int), stream);

    int eb = (EPE + 255) / 256;
    build_edges_kernel<<<eb, 256, 0, stream>>>(ei, src_all, dst_all, deg);
    scan_kernel<<<1, 1024, 0, stream>>>(deg, row_ptr, NN);
    scatter_kernel<<<eb, 256, 0, stream>>>(src_all, dst_all, row_ptr, cursor, col_src);

    const float* xin = X;
    for (int i = 0; i < 5; ++i) {
        int Fin = (i == 0) ? 200 : 800;
        int H   = (i == 4) ? 1 : 4;
        int HC  = H * CC;
        const float* W  = (const float*)d_in[2 + 4 * i];
        const float* as_ = (const float*)d_in[3 + 4 * i];
        const float* ad_ = (const float*)d_in[4 + 4 * i];
        const float* b_  = (const float*)d_in[5 + 4 * i];

        dim3 ggrid((HC + 63) / 64, (NN + 63) / 64);
        gemm_kernel<<<ggrid, 256, 0, stream>>>(xin, W, bufB, NN, Fin, HC);
        attn_kernel<<<NN, 256, 0, stream>>>(bufB, as_, ad_, asrc, adst, H, HC);

        float* aggout = (i == 4) ? (float*)d_out : bufA;
        agg_kernel<<<NN, 256, 0, stream>>>(bufB, asrc, adst, row_ptr, col_src, b_,
                                           aggout, m_arr, den_arr, H, HC);
        xin = bufA;
    }

    alpha_kernel<<<eb, 256, 0, stream>>>(src_all, dst_all, asrc, adst, m_arr, den_arr,
                                         (float*)d_out + (size_t)NN * CC);
}

// Round 2
// 1328.354 us; speedup vs baseline: 1.6896x; 1.6896x over previous
//
#include <hip/hip_runtime.h>
#include <math.h>

#define NN 10000
#define EE 100000
#define EPE 110000   // edges + self loops
#define CC 200
#define MPAD 10112   // 79 * 128

typedef __attribute__((ext_vector_type(8))) short bf16x8;
typedef __attribute__((ext_vector_type(4))) float f32x4;

__device__ __forceinline__ float lrelu(float v) { return v >= 0.f ? v : 0.2f * v; }
__device__ __forceinline__ float gelu_f(float v) { return 0.5f * v * (1.f + erff(v * 0.70710678118654752f)); }

__device__ __forceinline__ unsigned short f2bf(float f) {
    unsigned u = __builtin_bit_cast(unsigned, f);
    u += 0x7fff + ((u >> 16) & 1);   // round-to-nearest-even
    return (unsigned short)(u >> 16);
}
__device__ __forceinline__ float bf2f(unsigned short s) {
    return __builtin_bit_cast(float, (unsigned)s << 16);
}

// ---------------- CSR build ----------------

__global__ void build_edges_kernel(const int* __restrict__ ei,
                                   int* __restrict__ src_all, int* __restrict__ dst_all,
                                   int* __restrict__ deg) {
    int e = blockIdx.x * blockDim.x + threadIdx.x;
    if (e >= EPE) return;
    int s, d;
    if (e < EE) { s = ei[e]; d = ei[EE + e]; }
    else        { s = e - EE; d = e - EE; }
    src_all[e] = s;
    dst_all[e] = d;
    atomicAdd(&deg[d], 1);
}

__global__ void scan_kernel(const int* __restrict__ deg, int* __restrict__ row_ptr, int n) {
    __shared__ int sm[1024];
    int tid = threadIdx.x;
    int carry = 0;
    for (int base = 0; base < n; base += 1024) {
        int idx = base + tid;
        int v = (idx < n) ? deg[idx] : 0;
        sm[tid] = v;
        __syncthreads();
        for (int off = 1; off < 1024; off <<= 1) {
            int t = (tid >= off) ? sm[tid - off] : 0;
            __syncthreads();
            sm[tid] += t;
            __syncthreads();
        }
        if (idx < n) row_ptr[idx] = carry + sm[tid] - v;   // exclusive
        carry += sm[1023];
        __syncthreads();
    }
    if (tid == 0) row_ptr[n] = carry;
}

__global__ void scatter_kernel(const int* __restrict__ src_all, const int* __restrict__ dst_all,
                               const int* __restrict__ row_ptr, int* __restrict__ cursor,
                               int* __restrict__ col_src) {
    int e = blockIdx.x * blockDim.x + threadIdx.x;
    if (e >= EPE) return;
    int d = dst_all[e];
    int pos = row_ptr[d] + atomicAdd(&cursor[d], 1);
    col_src[pos] = src_all[e];
}

// ---------------- split-bf16 conversion ----------------
// A' = [A_hi | A_lo | A_hi] along K (each segment zero-padded to Kp)
__global__ void convA_kernel(const float* __restrict__ x, int sx, int Fin, int Kp,
                             unsigned short* __restrict__ Ap) {
    int Kt = 3 * Kp;
    size_t idx = (size_t)blockIdx.x * 256 + threadIdx.x;
    if (idx >= (size_t)MPAD * Kp) return;
    int row = (int)(idx / Kp);
    int kk  = (int)(idx % Kp);
    float v = 0.f;
    if (row < NN && kk < Fin) v = x[(size_t)row * sx + kk];
    unsigned short hu = f2bf(v);
    unsigned short lu = f2bf(v - bf2f(hu));
    size_t rb = (size_t)row * Kt;
    Ap[rb + kk] = hu;
    Ap[rb + Kp + kk] = lu;
    Ap[rb + 2 * Kp + kk] = hu;
}

// B' transposed to [n][k], segments [B_hi ; B_hi ; B_lo]
__global__ void convB_kernel(const float* __restrict__ W, int Fin, int HC, int Kp, int Np,
                             unsigned short* __restrict__ Bp) {
    int Kt = 3 * Kp;
    size_t idx = (size_t)blockIdx.x * 256 + threadIdx.x;
    if (idx >= (size_t)Np * Kp) return;
    int n  = (int)(idx / Kp);
    int kk = (int)(idx % Kp);
    float v = 0.f;
    if (n < HC && kk < Fin) v = W[(size_t)kk * HC + n];
    unsigned short hu = f2bf(v);
    unsigned short lu = f2bf(v - bf2f(hu));
    size_t rb = (size_t)n * Kt;
    Bp[rb + kk] = hu;
    Bp[rb + Kp + kk] = hu;
    Bp[rb + 2 * Kp + kk] = lu;
}

// ---------------- MFMA GEMM: C[MPAD x Np] = A'[MPAD x Kt] * B'[Np x Kt]^T ----------------
// 128x128 tile, BK=64, 4 waves, 16x16x32 bf16 MFMA, global_load_lds w16,
// XOR chunk swizzle (chunk ^= row&7) via pre-swizzled global source.

__global__ __launch_bounds__(256) void gemm_mfma(const unsigned short* __restrict__ A,
                                                 const unsigned short* __restrict__ B,
                                                 float* __restrict__ C,
                                                 int Kt, int Np) {
    __shared__ unsigned short As[8192];   // [128 rows][64 k] swizzled, 16 KB
    __shared__ unsigned short Bs[8192];   // [128 n-rows][64 k] swizzled

    int tid = threadIdx.x;
    int lane = tid & 63, wave = tid >> 6;
    int row0 = blockIdx.y * 128, col0 = blockIdx.x * 128;
    int wr = wave >> 1, wc = wave & 1;

    // staging addresses: 4 segments per wave for each of A,B
    size_t gAoff[4], gBoff[4];
    int ldsSeg[4];
#pragma unroll
    for (int i = 0; i < 4; ++i) {
        int seg = wave * 4 + i;            // 0..15
        int chunkIdx = seg * 64 + lane;    // 0..1023
        int r = chunkIdx >> 3;             // row 0..127
        int c = chunkIdx & 7;              // linear chunk in row
        int cg = c ^ (r & 7);              // pre-swizzled source chunk
        gAoff[i] = (size_t)(row0 + r) * Kt + (size_t)cg * 8;
        gBoff[i] = (size_t)(col0 + r) * Kt + (size_t)cg * 8;
        ldsSeg[i] = seg * 512;             // shorts (seg*1024 bytes)
    }

    // fragment read bases
    int rowA[4], rowB[4];
#pragma unroll
    for (int m = 0; m < 4; ++m) {
        rowA[m] = wr * 64 + m * 16 + (lane & 15);
        rowB[m] = wc * 64 + m * 16 + (lane & 15);
    }

    f32x4 acc[4][4];
#pragma unroll
    for (int m = 0; m < 4; ++m)
#pragma unroll
        for (int n = 0; n < 4; ++n) acc[m][n] = f32x4{0.f, 0.f, 0.f, 0.f};

    for (int k0 = 0; k0 < Kt; k0 += 64) {
#pragma unroll
        for (int i = 0; i < 4; ++i) {
            __builtin_amdgcn_global_load_lds(
                (const __attribute__((address_space(1))) void*)(A + gAoff[i] + k0),
                (__attribute__((address_space(3))) void*)(&As[ldsSeg[i]]), 16, 0, 0);
            __builtin_amdgcn_global_load_lds(
                (const __attribute__((address_space(1))) void*)(B + gBoff[i] + k0),
                (__attribute__((address_space(3))) void*)(&Bs[ldsSeg[i]]), 16, 0, 0);
        }
        __syncthreads();

#pragma unroll
        for (int kh = 0; kh < 2; ++kh) {
            int cw = kh * 4 + (lane >> 4);     // wanted chunk 0..7
            bf16x8 a[4], b[4];
#pragma unroll
            for (int m = 0; m < 4; ++m) {
                int ia = rowA[m] * 64 + ((cw ^ (rowA[m] & 7)) << 3);
                a[m] = *(const bf16x8*)(&As[ia]);
            }
#pragma unroll
            for (int n = 0; n < 4; ++n) {
                int ib = rowB[n] * 64 + ((cw ^ (rowB[n] & 7)) << 3);
                b[n] = *(const bf16x8*)(&Bs[ib]);
            }
#pragma unroll
            for (int m = 0; m < 4; ++m)
#pragma unroll
                for (int n = 0; n < 4; ++n)
                    acc[m][n] = __builtin_amdgcn_mfma_f32_16x16x32_bf16(a[m], b[n], acc[m][n], 0, 0, 0);
        }
        __syncthreads();
    }

    int crow = row0 + wr * 64 + ((lane >> 4) << 2);
    int ccol = col0 + wc * 64 + (lane & 15);
#pragma unroll
    for (int m = 0; m < 4; ++m)
#pragma unroll
        for (int j = 0; j < 4; ++j) {
            size_t rb = (size_t)(crow + m * 16 + j) * Np;
#pragma unroll
            for (int n = 0; n < 4; ++n)
                C[rb + ccol + n * 16] = acc[m][n][j];
        }
}

// ---------------- attention scores ----------------

__global__ void attn_kernel(const float* __restrict__ h,
                            const float* __restrict__ a_s, const float* __restrict__ a_d,
                            float* __restrict__ asrc, float* __restrict__ adst,
                            int H, int HCp) {
    int n = blockIdx.x;
    int wave = threadIdx.x >> 6;
    int lane = threadIdx.x & 63;
    if (wave >= H) return;
    float sa = 0.f, da = 0.f;
    const float* hrow = h + (size_t)n * HCp + wave * CC;
    for (int c = lane; c < CC; c += 64) {
        float hv = hrow[c];
        sa += hv * a_s[wave * CC + c];
        da += hv * a_d[wave * CC + c];
    }
#pragma unroll
    for (int off = 32; off > 0; off >>= 1) {
        sa += __shfl_down(sa, off);
        da += __shfl_down(da, off);
    }
    if (lane == 0) {
        asrc[n * H + wave] = sa;
        adst[n * H + wave] = da;
    }
}

// ---------------- per-dst segment softmax + aggregation + bias + gelu ----------------

__global__ __launch_bounds__(256) void agg_kernel(const float* __restrict__ h,
                                                  const float* __restrict__ asrc,
                                                  const float* __restrict__ adst,
                                                  const int* __restrict__ row_ptr,
                                                  const int* __restrict__ col_src,
                                                  const float* __restrict__ bias,
                                                  float* __restrict__ out,
                                                  float* __restrict__ m_out,
                                                  float* __restrict__ den_out,
                                                  int H, int HC, int HCp) {
    int n = blockIdx.x;
    int tid = threadIdx.x;
    __shared__ float w_lds[4];
    __shared__ float m_s[4], den_s[4], ad_s[4];
    int beg = row_ptr[n], end = row_ptr[n + 1];

    if (tid < H) {
        float ad = adst[n * H + tid];
        float mmax = -1e30f;
        for (int e = beg; e < end; ++e) {
            int s = col_src[e];
            float ev = lrelu(asrc[s * H + tid] + ad);
            mmax = fmaxf(mmax, ev);
        }
        float den = 0.f;
        for (int e = beg; e < end; ++e) {
            int s = col_src[e];
            float ev = lrelu(asrc[s * H + tid] + ad);
            den += expf(ev - mmax);
        }
        m_s[tid] = mmax; den_s[tid] = den; ad_s[tid] = ad;
        m_out[n * H + tid] = mmax;
        den_out[n * H + tid] = den;
    }
    __syncthreads();

    float acc[4] = {0.f, 0.f, 0.f, 0.f};
    for (int e = beg; e < end; ++e) {
        int s = col_src[e];
        if (tid < H) {
            float ev = lrelu(asrc[s * H + tid] + ad_s[tid]);
            w_lds[tid] = expf(ev - m_s[tid]) / den_s[tid];
        }
        __syncthreads();
        const float* hrow = h + (size_t)s * HCp;
#pragma unroll
        for (int k = 0; k < 4; ++k) {
            int hc = tid + k * 256;
            if (hc < HC) acc[k] += w_lds[hc / CC] * hrow[hc];
        }
        __syncthreads();
    }
#pragma unroll
    for (int k = 0; k < 4; ++k) {
        int hc = tid + k * 256;
        if (hc < HC) out[(size_t)n * HC + hc] = gelu_f(acc[k] + bias[hc]);
    }
}

// ---------------- layer-4 edge attention output ----------------

__global__ void alpha_kernel(const int* __restrict__ src_all, const int* __restrict__ dst_all,
                             const float* __restrict__ asrc, const float* __restrict__ adst,
                             const float* __restrict__ m, const float* __restrict__ den,
                             float* __restrict__ out_alpha) {
    int e = blockIdx.x * blockDim.x + threadIdx.x;
    if (e >= EPE) return;
    int s = src_all[e], d = dst_all[e];
    float ev = lrelu(asrc[s] + adst[d]);
    out_alpha[e] = expf(ev - m[d]) / den[d];
}

// ---------------- host ----------------

extern "C" void kernel_launch(void* const* d_in, const int* in_sizes, int n_in,
                              void* d_out, int out_size, void* d_ws, size_t ws_size,
                              hipStream_t stream) {
    const float* X = (const float*)d_in[0];
    const int* ei = (const int*)d_in[1];

    char* ws = (char*)d_ws;
    size_t off = 0;
    auto alloc = [&](size_t bytes) { void* p = ws + off; off += (bytes + 255) & ~(size_t)255; return p; };

    float* xbuf = (float*)alloc((size_t)NN * 800 * 4);              // 32 MB
    float* hbuf = (float*)alloc((size_t)MPAD * 896 * 4);            // 36.2 MB
    unsigned short* Ap = (unsigned short*)alloc((size_t)MPAD * 2496 * 2);  // 50.5 MB
    unsigned short* Bp = (unsigned short*)alloc((size_t)896 * 2496 * 2);   // 4.5 MB
    float* asrc   = (float*)alloc((size_t)NN * 4 * 4);
    float* adst   = (float*)alloc((size_t)NN * 4 * 4);
    float* m_arr  = (float*)alloc((size_t)NN * 4 * 4);
    float* den_arr= (float*)alloc((size_t)NN * 4 * 4);
    int* src_all  = (int*)alloc((size_t)EPE * 4);
    int* dst_all  = (int*)alloc((size_t)EPE * 4);
    int* col_src  = (int*)alloc((size_t)EPE * 4);
    int* row_ptr  = (int*)alloc((size_t)(NN + 1) * 4);
    int* deg      = (int*)alloc((size_t)NN * 4);
    int* cursor   = (int*)alloc((size_t)NN * 4);

    hipMemsetAsync(deg, 0, NN * sizeof(int), stream);
    hipMemsetAsync(cursor, 0, NN * sizeof(int), stream);

    int eb = (EPE + 255) / 256;
    build_edges_kernel<<<eb, 256, 0, stream>>>(ei, src_all, dst_all, deg);
    scan_kernel<<<1, 1024, 0, stream>>>(deg, row_ptr, NN);
    scatter_kernel<<<eb, 256, 0, stream>>>(src_all, dst_all, row_ptr, cursor, col_src);

    const float* xin = X;
    int sx = 200;
    for (int i = 0; i < 5; ++i) {
        int Fin = (i == 0) ? 200 : 800;
        int H   = (i == 4) ? 1 : 4;
        int HC  = H * CC;
        int Kp  = (Fin == 200) ? 256 : 832;
        int Kt  = 3 * Kp;
        int Np  = (HC == 800) ? 896 : 256;
        const float* W   = (const float*)d_in[2 + 4 * i];
        const float* as_ = (const float*)d_in[3 + 4 * i];
        const float* ad_ = (const float*)d_in[4 + 4 * i];
        const float* b_  = (const float*)d_in[5 + 4 * i];

        size_t na = (size_t)MPAD * Kp;
        convA_kernel<<<(int)((na + 255) / 256), 256, 0, stream>>>(xin, sx, Fin, Kp, Ap);
        size_t nb = (size_t)Np * Kp;
        convB_kernel<<<(int)((nb + 255) / 256), 256, 0, stream>>>(W, Fin, HC, Kp, Np, Bp);

        gemm_mfma<<<dim3(Np / 128, MPAD / 128), 256, 0, stream>>>(Ap, Bp, hbuf, Kt, Np);

        attn_kernel<<<NN, 256, 0, stream>>>(hbuf, as_, ad_, asrc, adst, H, Np);

        float* aggout = (i == 4) ? (float*)d_out : xbuf;
        agg_kernel<<<NN, 256, 0, stream>>>(hbuf, asrc, adst, row_ptr, col_src, b_,
                                           aggout, m_arr, den_arr, H, HC, Np);
        xin = xbuf;
        sx = 800;
    }

    alpha_kernel<<<eb, 256, 0, stream>>>(src_all, dst_all, asrc, adst, m_arr, den_arr,
                                         (float*)d_out + (size_t)NN * CC);
}

// Round 3
// 969.770 us; speedup vs baseline: 2.3144x; 1.3698x over previous
//
#include <hip/hip_runtime.h>
#include <math.h>

#define NN 10000
#define EE 100000
#define EPE 110000   // edges + self loops
#define CC 200
#define MPAD 10112   // 79 * 128

typedef __attribute__((ext_vector_type(8))) short bf16x8;
typedef __attribute__((ext_vector_type(4))) float f32x4;

__device__ __forceinline__ float lrelu(float v) { return v >= 0.f ? v : 0.2f * v; }
__device__ __forceinline__ float gelu_f(float v) { return 0.5f * v * (1.f + erff(v * 0.70710678118654752f)); }

__device__ __forceinline__ unsigned short f2bf(float f) {
    unsigned u = __builtin_bit_cast(unsigned, f);
    u += 0x7fff + ((u >> 16) & 1);   // round-to-nearest-even
    return (unsigned short)(u >> 16);
}
__device__ __forceinline__ float bf2f(unsigned short s) {
    return __builtin_bit_cast(float, (unsigned)s << 16);
}

// ---------------- CSR build ----------------

__global__ void build_edges_kernel(const int* __restrict__ ei,
                                   int* __restrict__ src_all, int* __restrict__ dst_all,
                                   int* __restrict__ deg) {
    int e = blockIdx.x * blockDim.x + threadIdx.x;
    if (e >= EPE) return;
    int s, d;
    if (e < EE) { s = ei[e]; d = ei[EE + e]; }
    else        { s = e - EE; d = e - EE; }
    src_all[e] = s;
    dst_all[e] = d;
    atomicAdd(&deg[d], 1);
}

__global__ void scan_kernel(const int* __restrict__ deg, int* __restrict__ row_ptr, int n) {
    __shared__ int sm[1024];
    int tid = threadIdx.x;
    int carry = 0;
    for (int base = 0; base < n; base += 1024) {
        int idx = base + tid;
        int v = (idx < n) ? deg[idx] : 0;
        sm[tid] = v;
        __syncthreads();
        for (int off = 1; off < 1024; off <<= 1) {
            int t = (tid >= off) ? sm[tid - off] : 0;
            __syncthreads();
            sm[tid] += t;
            __syncthreads();
        }
        if (idx < n) row_ptr[idx] = carry + sm[tid] - v;   // exclusive
        carry += sm[1023];
        __syncthreads();
    }
    if (tid == 0) row_ptr[n] = carry;
}

__global__ void scatter_kernel(const int* __restrict__ src_all, const int* __restrict__ dst_all,
                               const int* __restrict__ row_ptr, int* __restrict__ cursor,
                               int* __restrict__ col_src, int* __restrict__ col_eid) {
    int e = blockIdx.x * blockDim.x + threadIdx.x;
    if (e >= EPE) return;
    int d = dst_all[e];
    int pos = row_ptr[d] + atomicAdd(&cursor[d], 1);
    col_src[pos] = src_all[e];
    col_eid[pos] = e;
}

// ---------------- split-bf16 conversion ----------------
// A' = [A_hi | A_lo | A_hi] along K (each segment zero-padded to Kp)
__global__ void convA_kernel(const float* __restrict__ x, int sx, int Fin, int Kp,
                             unsigned short* __restrict__ Ap) {
    int Kt = 3 * Kp;
    size_t idx = (size_t)blockIdx.x * 256 + threadIdx.x;
    if (idx >= (size_t)MPAD * Kp) return;
    int row = (int)(idx / Kp);
    int kk  = (int)(idx % Kp);
    float v = 0.f;
    if (row < NN && kk < Fin) v = x[(size_t)row * sx + kk];
    unsigned short hu = f2bf(v);
    unsigned short lu = f2bf(v - bf2f(hu));
    size_t rb = (size_t)row * Kt;
    Ap[rb + kk] = hu;
    Ap[rb + Kp + kk] = lu;
    Ap[rb + 2 * Kp + kk] = hu;
}

// B' transposed to [n][k], segments [B_hi ; B_hi ; B_lo]
__global__ void convB_kernel(const float* __restrict__ W, int Fin, int HC, int Kp, int Np,
                             unsigned short* __restrict__ Bp) {
    int Kt = 3 * Kp;
    size_t idx = (size_t)blockIdx.x * 256 + threadIdx.x;
    if (idx >= (size_t)Np * Kp) return;
    int n  = (int)(idx / Kp);
    int kk = (int)(idx % Kp);
    float v = 0.f;
    if (n < HC && kk < Fin) v = W[(size_t)kk * HC + n];
    unsigned short hu = f2bf(v);
    unsigned short lu = f2bf(v - bf2f(hu));
    size_t rb = (size_t)n * Kt;
    Bp[rb + kk] = hu;
    Bp[rb + Kp + kk] = hu;
    Bp[rb + 2 * Kp + kk] = lu;
}

// ---------------- MFMA GEMM: C[MPAD x Np] = A'[MPAD x Kt] * B'[Np x Kt]^T ----------------

__global__ __launch_bounds__(256) void gemm_mfma(const unsigned short* __restrict__ A,
                                                 const unsigned short* __restrict__ B,
                                                 float* __restrict__ C,
                                                 int Kt, int Np) {
    __shared__ unsigned short As[8192];   // [128 rows][64 k] swizzled, 16 KB
    __shared__ unsigned short Bs[8192];   // [128 n-rows][64 k] swizzled

    int tid = threadIdx.x;
    int lane = tid & 63, wave = tid >> 6;
    int row0 = blockIdx.y * 128, col0 = blockIdx.x * 128;
    int wr = wave >> 1, wc = wave & 1;

    size_t gAoff[4], gBoff[4];
    int ldsSeg[4];
#pragma unroll
    for (int i = 0; i < 4; ++i) {
        int seg = wave * 4 + i;            // 0..15
        int chunkIdx = seg * 64 + lane;    // 0..1023
        int r = chunkIdx >> 3;             // row 0..127
        int c = chunkIdx & 7;              // linear chunk in row
        int cg = c ^ (r & 7);              // pre-swizzled source chunk
        gAoff[i] = (size_t)(row0 + r) * Kt + (size_t)cg * 8;
        gBoff[i] = (size_t)(col0 + r) * Kt + (size_t)cg * 8;
        ldsSeg[i] = seg * 512;             // shorts (seg*1024 bytes)
    }

    int rowA[4], rowB[4];
#pragma unroll
    for (int m = 0; m < 4; ++m) {
        rowA[m] = wr * 64 + m * 16 + (lane & 15);
        rowB[m] = wc * 64 + m * 16 + (lane & 15);
    }

    f32x4 acc[4][4];
#pragma unroll
    for (int m = 0; m < 4; ++m)
#pragma unroll
        for (int n = 0; n < 4; ++n) acc[m][n] = f32x4{0.f, 0.f, 0.f, 0.f};

    for (int k0 = 0; k0 < Kt; k0 += 64) {
#pragma unroll
        for (int i = 0; i < 4; ++i) {
            __builtin_amdgcn_global_load_lds(
                (const __attribute__((address_space(1))) void*)(A + gAoff[i] + k0),
                (__attribute__((address_space(3))) void*)(&As[ldsSeg[i]]), 16, 0, 0);
            __builtin_amdgcn_global_load_lds(
                (const __attribute__((address_space(1))) void*)(B + gBoff[i] + k0),
                (__attribute__((address_space(3))) void*)(&Bs[ldsSeg[i]]), 16, 0, 0);
        }
        __syncthreads();

#pragma unroll
        for (int kh = 0; kh < 2; ++kh) {
            int cw = kh * 4 + (lane >> 4);     // wanted chunk 0..7
            bf16x8 a[4], b[4];
#pragma unroll
            for (int m = 0; m < 4; ++m) {
                int ia = rowA[m] * 64 + ((cw ^ (rowA[m] & 7)) << 3);
                a[m] = *(const bf16x8*)(&As[ia]);
            }
#pragma unroll
            for (int n = 0; n < 4; ++n) {
                int ib = rowB[n] * 64 + ((cw ^ (rowB[n] & 7)) << 3);
                b[n] = *(const bf16x8*)(&Bs[ib]);
            }
#pragma unroll
            for (int m = 0; m < 4; ++m)
#pragma unroll
                for (int n = 0; n < 4; ++n)
                    acc[m][n] = __builtin_amdgcn_mfma_f32_16x16x32_bf16(a[m], b[n], acc[m][n], 0, 0, 0);
        }
        __syncthreads();
    }

    int crow = row0 + wr * 64 + ((lane >> 4) << 2);
    int ccol = col0 + wc * 64 + (lane & 15);
#pragma unroll
    for (int m = 0; m < 4; ++m)
#pragma unroll
        for (int j = 0; j < 4; ++j) {
            size_t rb = (size_t)(crow + m * 16 + j) * Np;
#pragma unroll
            for (int n = 0; n < 4; ++n)
                C[rb + ccol + n * 16] = acc[m][n][j];
        }
}

// ---------------- attention scores ----------------

__global__ void attn_kernel(const float* __restrict__ h,
                            const float* __restrict__ a_s, const float* __restrict__ a_d,
                            float* __restrict__ asrc, float* __restrict__ adst,
                            int H, int HCp) {
    int n = blockIdx.x;
    int wave = threadIdx.x >> 6;
    int lane = threadIdx.x & 63;
    if (wave >= H) return;
    float sa = 0.f, da = 0.f;
    const float* hrow = h + (size_t)n * HCp + wave * CC;
    for (int c = lane; c < CC; c += 64) {
        float hv = hrow[c];
        sa += hv * a_s[wave * CC + c];
        da += hv * a_d[wave * CC + c];
    }
#pragma unroll
    for (int off = 32; off > 0; off >>= 1) {
        sa += __shfl_down(sa, off);
        da += __shfl_down(da, off);
    }
    if (lane == 0) {
        asrc[n * H + wave] = sa;
        adst[n * H + wave] = da;
    }
}

// ---------------- per-(node,head) online softmax m/den ----------------

__global__ void mden_kernel(const float* __restrict__ asrc, const float* __restrict__ adst,
                            const int* __restrict__ row_ptr, const int* __restrict__ col_src,
                            float* __restrict__ m_arr, float* __restrict__ den_arr, int H) {
    int i = blockIdx.x * blockDim.x + threadIdx.x;
    if (i >= NN * H) return;
    int n = i / H, hd = i - n * H;
    float ad = adst[i];
    int beg = row_ptr[n], end = row_ptr[n + 1];
    float m = -1e30f, den = 0.f;
    for (int e = beg; e < end; ++e) {
        int s = col_src[e];
        float v = lrelu(asrc[s * H + hd] + ad);
        if (v > m) { den = den * expf(m - v) + 1.f; m = v; }
        else den += expf(v - m);
    }
    m_arr[i] = m;
    den_arr[i] = den;
}

// ---------------- per-(edge,head) softmax weight, original edge order ----------------

__global__ void weight_kernel(const int* __restrict__ src_all, const int* __restrict__ dst_all,
                              const float* __restrict__ asrc, const float* __restrict__ adst,
                              const float* __restrict__ m_arr, const float* __restrict__ den_arr,
                              float* __restrict__ w, int H) {
    int i = blockIdx.x * blockDim.x + threadIdx.x;
    if (i >= EPE * H) return;
    int e = i / H, hd = i - e * H;
    int s = src_all[e], d = dst_all[e];
    float v = lrelu(asrc[s * H + hd] + adst[d * H + hd]);
    w[i] = expf(v - m_arr[d * H + hd]) / den_arr[d * H + hd];
}

// ---------------- weighted aggregation + bias + gelu (no syncthreads) ----------------

__global__ __launch_bounds__(256) void agg2_kernel(const float* __restrict__ h,
                                                   const float* __restrict__ w,
                                                   const int* __restrict__ row_ptr,
                                                   const int* __restrict__ col_src,
                                                   const int* __restrict__ col_eid,
                                                   const float* __restrict__ bias,
                                                   float* __restrict__ out,
                                                   int H, int HC, int HCp) {
    int n = blockIdx.x;
    int hc0 = threadIdx.x * 4;
    if (hc0 >= HC) return;
    int head = hc0 / CC;
    int beg = row_ptr[n], end = row_ptr[n + 1];

    float4 acc = {0.f, 0.f, 0.f, 0.f};
    int s = col_src[beg], eid = col_eid[beg];
    for (int e = beg; e < end; ++e) {
        int s_next = s, eid_next = eid;
        if (e + 1 < end) { s_next = col_src[e + 1]; eid_next = col_eid[e + 1]; }
        float wv = w[(size_t)eid * H + head];
        float4 hv = *(const float4*)(h + (size_t)s * HCp + hc0);
        acc.x += wv * hv.x;
        acc.y += wv * hv.y;
        acc.z += wv * hv.z;
        acc.w += wv * hv.w;
        s = s_next; eid = eid_next;
    }
    float4 bv = *(const float4*)(bias + hc0);
    float4 o;
    o.x = gelu_f(acc.x + bv.x);
    o.y = gelu_f(acc.y + bv.y);
    o.z = gelu_f(acc.z + bv.z);
    o.w = gelu_f(acc.w + bv.w);
    *(float4*)(out + (size_t)n * HC + hc0) = o;
}

// ---------------- host ----------------

extern "C" void kernel_launch(void* const* d_in, const int* in_sizes, int n_in,
                              void* d_out, int out_size, void* d_ws, size_t ws_size,
                              hipStream_t stream) {
    const float* X = (const float*)d_in[0];
    const int* ei = (const int*)d_in[1];

    char* ws = (char*)d_ws;
    size_t off = 0;
    auto alloc = [&](size_t bytes) { void* p = ws + off; off += (bytes + 255) & ~(size_t)255; return p; };

    float* xbuf = (float*)alloc((size_t)NN * 800 * 4);              // 32 MB
    float* hbuf = (float*)alloc((size_t)MPAD * 896 * 4);            // 36.2 MB
    unsigned short* Ap = (unsigned short*)alloc((size_t)MPAD * 2496 * 2);  // 50.5 MB
    unsigned short* Bp = (unsigned short*)alloc((size_t)896 * 2496 * 2);   // 4.5 MB
    float* asrc   = (float*)alloc((size_t)NN * 4 * 4);
    float* adst   = (float*)alloc((size_t)NN * 4 * 4);
    float* m_arr  = (float*)alloc((size_t)NN * 4 * 4);
    float* den_arr= (float*)alloc((size_t)NN * 4 * 4);
    float* wbuf   = (float*)alloc((size_t)EPE * 4 * 4);
    int* src_all  = (int*)alloc((size_t)EPE * 4);
    int* dst_all  = (int*)alloc((size_t)EPE * 4);
    int* col_src  = (int*)alloc((size_t)EPE * 4);
    int* col_eid  = (int*)alloc((size_t)EPE * 4);
    int* row_ptr  = (int*)alloc((size_t)(NN + 1) * 4);
    int* deg      = (int*)alloc((size_t)NN * 4);
    int* cursor   = (int*)alloc((size_t)NN * 4);

    hipMemsetAsync(deg, 0, NN * sizeof(int), stream);
    hipMemsetAsync(cursor, 0, NN * sizeof(int), stream);

    int eb = (EPE + 255) / 256;
    build_edges_kernel<<<eb, 256, 0, stream>>>(ei, src_all, dst_all, deg);
    scan_kernel<<<1, 1024, 0, stream>>>(deg, row_ptr, NN);
    scatter_kernel<<<eb, 256, 0, stream>>>(src_all, dst_all, row_ptr, cursor, col_src, col_eid);

    const float* xin = X;
    int sx = 200;
    for (int i = 0; i < 5; ++i) {
        int Fin = (i == 0) ? 200 : 800;
        int H   = (i == 4) ? 1 : 4;
        int HC  = H * CC;
        int Kp  = (Fin == 200) ? 256 : 832;
        int Kt  = 3 * Kp;
        int Np  = (HC == 800) ? 896 : 256;
        const float* W   = (const float*)d_in[2 + 4 * i];
        const float* as_ = (const float*)d_in[3 + 4 * i];
        const float* ad_ = (const float*)d_in[4 + 4 * i];
        const float* b_  = (const float*)d_in[5 + 4 * i];

        size_t na = (size_t)MPAD * Kp;
        convA_kernel<<<(int)((na + 255) / 256), 256, 0, stream>>>(xin, sx, Fin, Kp, Ap);
        size_t nb = (size_t)Np * Kp;
        convB_kernel<<<(int)((nb + 255) / 256), 256, 0, stream>>>(W, Fin, HC, Kp, Np, Bp);

        gemm_mfma<<<dim3(Np / 128, MPAD / 128), 256, 0, stream>>>(Ap, Bp, hbuf, Kt, Np);

        attn_kernel<<<NN, 256, 0, stream>>>(hbuf, as_, ad_, asrc, adst, H, Np);

        mden_kernel<<<(NN * H + 255) / 256, 256, 0, stream>>>(asrc, adst, row_ptr, col_src,
                                                              m_arr, den_arr, H);

        float* wptr = (i == 4) ? (float*)d_out + (size_t)NN * CC : wbuf;
        weight_kernel<<<(EPE * H + 255) / 256, 256, 0, stream>>>(src_all, dst_all, asrc, adst,
                                                                 m_arr, den_arr, wptr, H);

        float* aggout = (i == 4) ? (float*)d_out : xbuf;
        agg2_kernel<<<NN, 256, 0, stream>>>(hbuf, wptr, row_ptr, col_src, col_eid, b_,
                                            aggout, H, HC, Np);
        xin = xbuf;
        sx = 800;
    }
}

// Round 4
// 643.393 us; speedup vs baseline: 3.4884x; 1.5073x over previous
//
#include <hip/hip_runtime.h>
#include <math.h>

#define NN 10000
#define EE 100000
#define EPE 110000   // edges + self loops
#define CC 200
#define MPAD 10112   // 79 * 128

typedef __attribute__((ext_vector_type(8))) _Float16 f16x8;
typedef __attribute__((ext_vector_type(4))) _Float16 f16x4;
typedef __attribute__((ext_vector_type(4))) unsigned short u16x4;
typedef __attribute__((ext_vector_type(4))) float f32x4;

__device__ __forceinline__ float lrelu(float v) { return v >= 0.f ? v : 0.2f * v; }
__device__ __forceinline__ float gelu_f(float v) { return 0.5f * v * (1.f + erff(v * 0.70710678118654752f)); }

// ---------------- CSR build ----------------

__global__ void build_edges_kernel(const int* __restrict__ ei,
                                   int* __restrict__ src_all, int* __restrict__ dst_all,
                                   int* __restrict__ deg) {
    int e = blockIdx.x * blockDim.x + threadIdx.x;
    if (e >= EPE) return;
    int s, d;
    if (e < EE) { s = ei[e]; d = ei[EE + e]; }
    else        { s = e - EE; d = e - EE; }
    src_all[e] = s;
    dst_all[e] = d;
    atomicAdd(&deg[d], 1);
}

__global__ void scan_kernel(const int* __restrict__ deg, int* __restrict__ row_ptr, int n) {
    __shared__ int sm[1024];
    int tid = threadIdx.x;
    int carry = 0;
    for (int base = 0; base < n; base += 1024) {
        int idx = base + tid;
        int v = (idx < n) ? deg[idx] : 0;
        sm[tid] = v;
        __syncthreads();
        for (int off = 1; off < 1024; off <<= 1) {
            int t = (tid >= off) ? sm[tid - off] : 0;
            __syncthreads();
            sm[tid] += t;
            __syncthreads();
        }
        if (idx < n) row_ptr[idx] = carry + sm[tid] - v;   // exclusive
        carry += sm[1023];
        __syncthreads();
    }
    if (tid == 0) row_ptr[n] = carry;
}

__global__ void scatter_kernel(const int* __restrict__ src_all, const int* __restrict__ dst_all,
                               const int* __restrict__ row_ptr, int* __restrict__ cursor,
                               int* __restrict__ col_src, int* __restrict__ col_eid) {
    int e = blockIdx.x * blockDim.x + threadIdx.x;
    if (e >= EPE) return;
    int d = dst_all[e];
    int pos = row_ptr[d] + atomicAdd(&cursor[d], 1);
    col_src[pos] = src_all[e];
    col_eid[pos] = e;
}

// ---------------- fp16 2-term split conversion ----------------
// A' = [A_hi | A_lo] along K (each segment Kp wide, zero-padded)
__global__ void convA_kernel(const float* __restrict__ x, int sx, int Fin, int Kp,
                             unsigned short* __restrict__ Ap) {
    int Kt = 2 * Kp;
    size_t idx = (size_t)blockIdx.x * 256 + threadIdx.x;
    if (idx >= (size_t)MPAD * Kp) return;
    int row = (int)(idx / Kp);
    int kk  = (int)(idx % Kp);
    float v = 0.f;
    if (row < NN && kk < Fin) v = x[(size_t)row * sx + kk];
    _Float16 hi = (_Float16)v;
    _Float16 lo = (_Float16)(v - (float)hi);
    size_t rb = (size_t)row * Kt;
    Ap[rb + kk]      = __builtin_bit_cast(unsigned short, hi);
    Ap[rb + Kp + kk] = __builtin_bit_cast(unsigned short, lo);
}

// B' transposed to [n][k], segments [B_hi ; B_hi]
__global__ void convB_kernel(const float* __restrict__ W, int Fin, int HC, int Kp, int Np,
                             unsigned short* __restrict__ Bp) {
    int Kt = 2 * Kp;
    size_t idx = (size_t)blockIdx.x * 256 + threadIdx.x;
    if (idx >= (size_t)Np * Kp) return;
    int n  = (int)(idx / Kp);
    int kk = (int)(idx % Kp);
    float v = 0.f;
    if (n < HC && kk < Fin) v = W[(size_t)kk * HC + n];
    unsigned short hu = __builtin_bit_cast(unsigned short, (_Float16)v);
    size_t rb = (size_t)n * Kt;
    Bp[rb + kk]      = hu;
    Bp[rb + Kp + kk] = hu;
}

// ---------------- MFMA GEMM: C[MPAD x Np](fp16) = A'[MPAD x Kt] * B'[Np x Kt]^T ----------------
// 128x128 tile, BK=64, 4 waves, 16x16x32 f16 MFMA, global_load_lds w16,
// XOR chunk swizzle via pre-swizzled global source, XCD-bijective block swizzle.

__global__ __launch_bounds__(256) void gemm_mfma(const unsigned short* __restrict__ A,
                                                 const unsigned short* __restrict__ B,
                                                 unsigned short* __restrict__ C,
                                                 int Kt, int Np, int ncol) {
    __shared__ unsigned short As[8192];   // [128 rows][64 k] swizzled, 16 KB
    __shared__ unsigned short Bs[8192];

    int tid = threadIdx.x;
    int lane = tid & 63, wave = tid >> 6;

    // XCD-bijective swizzle (m204): consecutive wg on one XCD share an A row-panel
    int nwg = gridDim.x;
    int orig = blockIdx.x;
    int q = nwg >> 3, r = nwg & 7;
    int xcd = orig & 7, sidx = orig >> 3;
    int wg = (xcd < r ? xcd * (q + 1) : r * (q + 1) + (xcd - r) * q) + sidx;
    int rowT = wg / ncol, colT = wg - rowT * ncol;
    int row0 = rowT * 128, col0 = colT * 128;
    int wr = wave >> 1, wc = wave & 1;

    size_t gAoff[4], gBoff[4];
    int ldsSeg[4];
#pragma unroll
    for (int i = 0; i < 4; ++i) {
        int seg = wave * 4 + i;            // 0..15
        int chunkIdx = seg * 64 + lane;    // 0..1023
        int rr = chunkIdx >> 3;            // row 0..127
        int c = chunkIdx & 7;
        int cg = c ^ (rr & 7);             // pre-swizzled source chunk
        gAoff[i] = (size_t)(row0 + rr) * Kt + (size_t)cg * 8;
        gBoff[i] = (size_t)(col0 + rr) * Kt + (size_t)cg * 8;
        ldsSeg[i] = seg * 512;
    }

    int rowA[4], rowB[4];
#pragma unroll
    for (int m = 0; m < 4; ++m) {
        rowA[m] = wr * 64 + m * 16 + (lane & 15);
        rowB[m] = wc * 64 + m * 16 + (lane & 15);
    }

    f32x4 acc[4][4];
#pragma unroll
    for (int m = 0; m < 4; ++m)
#pragma unroll
        for (int n = 0; n < 4; ++n) acc[m][n] = f32x4{0.f, 0.f, 0.f, 0.f};

    for (int k0 = 0; k0 < Kt; k0 += 64) {
#pragma unroll
        for (int i = 0; i < 4; ++i) {
            __builtin_amdgcn_global_load_lds(
                (const __attribute__((address_space(1))) void*)(A + gAoff[i] + k0),
                (__attribute__((address_space(3))) void*)(&As[ldsSeg[i]]), 16, 0, 0);
            __builtin_amdgcn_global_load_lds(
                (const __attribute__((address_space(1))) void*)(B + gBoff[i] + k0),
                (__attribute__((address_space(3))) void*)(&Bs[ldsSeg[i]]), 16, 0, 0);
        }
        __syncthreads();

#pragma unroll
        for (int kh = 0; kh < 2; ++kh) {
            int cw = kh * 4 + (lane >> 4);
            f16x8 a[4], b[4];
#pragma unroll
            for (int m = 0; m < 4; ++m) {
                int ia = rowA[m] * 64 + ((cw ^ (rowA[m] & 7)) << 3);
                a[m] = *(const f16x8*)(&As[ia]);
            }
#pragma unroll
            for (int n = 0; n < 4; ++n) {
                int ib = rowB[n] * 64 + ((cw ^ (rowB[n] & 7)) << 3);
                b[n] = *(const f16x8*)(&Bs[ib]);
            }
#pragma unroll
            for (int m = 0; m < 4; ++m)
#pragma unroll
                for (int n = 0; n < 4; ++n)
                    acc[m][n] = __builtin_amdgcn_mfma_f32_16x16x32_f16(a[m], b[n], acc[m][n], 0, 0, 0);
        }
        __syncthreads();
    }

    int crow = row0 + wr * 64 + ((lane >> 4) << 2);
    int ccol = col0 + wc * 64 + (lane & 15);
#pragma unroll
    for (int m = 0; m < 4; ++m)
#pragma unroll
        for (int j = 0; j < 4; ++j) {
            size_t rb = (size_t)(crow + m * 16 + j) * Np;
#pragma unroll
            for (int n = 0; n < 4; ++n)
                C[rb + ccol + n * 16] =
                    __builtin_bit_cast(unsigned short, (_Float16)acc[m][n][j]);
        }
}

// ---------------- attention scores (fp16 h) ----------------

__global__ void attn_kernel(const unsigned short* __restrict__ h,
                            const float* __restrict__ a_s, const float* __restrict__ a_d,
                            float* __restrict__ asrc, float* __restrict__ adst,
                            int H, int HCp) {
    int n = blockIdx.x;
    int wave = threadIdx.x >> 6;
    int lane = threadIdx.x & 63;
    if (wave >= H) return;
    float sa = 0.f, da = 0.f;
    const unsigned short* hrow = h + (size_t)n * HCp + wave * CC;
    for (int c = lane; c < CC; c += 64) {
        float hv = (float)__builtin_bit_cast(_Float16, hrow[c]);
        sa += hv * a_s[wave * CC + c];
        da += hv * a_d[wave * CC + c];
    }
#pragma unroll
    for (int off = 32; off > 0; off >>= 1) {
        sa += __shfl_down(sa, off);
        da += __shfl_down(da, off);
    }
    if (lane == 0) {
        asrc[n * H + wave] = sa;
        adst[n * H + wave] = da;
    }
}

// ---------------- per-(node,head) online softmax m/den ----------------

__global__ void mden_kernel(const float* __restrict__ asrc, const float* __restrict__ adst,
                            const int* __restrict__ row_ptr, const int* __restrict__ col_src,
                            float* __restrict__ m_arr, float* __restrict__ den_arr, int H) {
    int i = blockIdx.x * blockDim.x + threadIdx.x;
    if (i >= NN * H) return;
    int n = i / H, hd = i - n * H;
    float ad = adst[i];
    int beg = row_ptr[n], end = row_ptr[n + 1];
    float m = -1e30f, den = 0.f;
    for (int e = beg; e < end; ++e) {
        int s = col_src[e];
        float v = lrelu(asrc[s * H + hd] + ad);
        if (v > m) { den = den * expf(m - v) + 1.f; m = v; }
        else den += expf(v - m);
    }
    m_arr[i] = m;
    den_arr[i] = den;
}

// ---------------- per-(edge,head) softmax weight, original edge order ----------------

__global__ void weight_kernel(const int* __restrict__ src_all, const int* __restrict__ dst_all,
                              const float* __restrict__ asrc, const float* __restrict__ adst,
                              const float* __restrict__ m_arr, const float* __restrict__ den_arr,
                              float* __restrict__ w, int H) {
    int i = blockIdx.x * blockDim.x + threadIdx.x;
    if (i >= EPE * H) return;
    int e = i / H, hd = i - e * H;
    int s = src_all[e], d = dst_all[e];
    float v = lrelu(asrc[s * H + hd] + adst[d * H + hd]);
    w[i] = expf(v - m_arr[d * H + hd]) / den_arr[d * H + hd];
}

// ---------------- aggregation + bias + gelu; writes next layer's A' split or d_out ----------------

__global__ __launch_bounds__(256) void agg3_kernel(const unsigned short* __restrict__ h,
                                                   const float* __restrict__ w,
                                                   const int* __restrict__ row_ptr,
                                                   const int* __restrict__ col_src,
                                                   const int* __restrict__ col_eid,
                                                   const float* __restrict__ bias,
                                                   float* __restrict__ out32,
                                                   unsigned short* __restrict__ apn,
                                                   int H, int HC, int HCp) {
    int n = blockIdx.x;
    int hc0 = threadIdx.x * 4;
    if (hc0 >= HC) return;
    int head = hc0 / CC;
    int beg = row_ptr[n], end = row_ptr[n + 1];

    float a0 = 0.f, a1 = 0.f, a2 = 0.f, a3 = 0.f;
    // 1-deep prefetch pipeline (T14): indices, weight, h-row
    int s = col_src[beg], eid = col_eid[beg];
    float wv = w[(size_t)eid * H + head];
    f16x4 hv = *(const f16x4*)(h + (size_t)s * HCp + hc0);
    for (int e = beg; e < end; ++e) {
        int s2 = 0, eid2 = 0; float wv2 = 0.f; f16x4 hv2 = {};
        if (e + 1 < end) {
            s2 = col_src[e + 1]; eid2 = col_eid[e + 1];
            wv2 = w[(size_t)eid2 * H + head];
            hv2 = *(const f16x4*)(h + (size_t)s2 * HCp + hc0);
        }
        a0 += wv * (float)hv[0];
        a1 += wv * (float)hv[1];
        a2 += wv * (float)hv[2];
        a3 += wv * (float)hv[3];
        s = s2; eid = eid2; wv = wv2; hv = hv2;
    }
    float4 bv = *(const float4*)(bias + hc0);
    float g0 = gelu_f(a0 + bv.x), g1 = gelu_f(a1 + bv.y);
    float g2 = gelu_f(a2 + bv.z), g3 = gelu_f(a3 + bv.w);
    if (out32) {
        *(float4*)(out32 + (size_t)n * HC + hc0) = float4{g0, g1, g2, g3};
    } else {
        // fp16 hi/lo split into next layer's A' [row][1664], Kp=832
        _Float16 h0 = (_Float16)g0, h1 = (_Float16)g1, h2 = (_Float16)g2, h3 = (_Float16)g3;
        _Float16 l0 = (_Float16)(g0 - (float)h0), l1 = (_Float16)(g1 - (float)h1);
        _Float16 l2 = (_Float16)(g2 - (float)h2), l3 = (_Float16)(g3 - (float)h3);
        size_t rb = (size_t)n * 1664;
        *(u16x4*)(apn + rb + hc0) = u16x4{
            __builtin_bit_cast(unsigned short, h0), __builtin_bit_cast(unsigned short, h1),
            __builtin_bit_cast(unsigned short, h2), __builtin_bit_cast(unsigned short, h3)};
        *(u16x4*)(apn + rb + 832 + hc0) = u16x4{
            __builtin_bit_cast(unsigned short, l0), __builtin_bit_cast(unsigned short, l1),
            __builtin_bit_cast(unsigned short, l2), __builtin_bit_cast(unsigned short, l3)};
    }
}

// ---------------- host ----------------

extern "C" void kernel_launch(void* const* d_in, const int* in_sizes, int n_in,
                              void* d_out, int out_size, void* d_ws, size_t ws_size,
                              hipStream_t stream) {
    const float* X = (const float*)d_in[0];
    const int* ei = (const int*)d_in[1];

    char* ws = (char*)d_ws;
    size_t off = 0;
    auto alloc = [&](size_t bytes) { void* p = ws + off; off += (bytes + 255) & ~(size_t)255; return p; };

    unsigned short* Ap0 = (unsigned short*)alloc((size_t)MPAD * 512 * 2);   // 10.4 MB
    unsigned short* Ap  = (unsigned short*)alloc((size_t)MPAD * 1664 * 2);  // 33.7 MB
    unsigned short* Bp  = (unsigned short*)alloc((size_t)896 * 1664 * 2);   // 3.0 MB
    unsigned short* hbuf= (unsigned short*)alloc((size_t)MPAD * 896 * 2);   // 18.1 MB
    float* asrc   = (float*)alloc((size_t)NN * 4 * 4);
    float* adst   = (float*)alloc((size_t)NN * 4 * 4);
    float* m_arr  = (float*)alloc((size_t)NN * 4 * 4);
    float* den_arr= (float*)alloc((size_t)NN * 4 * 4);
    float* wbuf   = (float*)alloc((size_t)EPE * 4 * 4);
    int* src_all  = (int*)alloc((size_t)EPE * 4);
    int* dst_all  = (int*)alloc((size_t)EPE * 4);
    int* col_src  = (int*)alloc((size_t)EPE * 4);
    int* col_eid  = (int*)alloc((size_t)EPE * 4);
    int* row_ptr  = (int*)alloc((size_t)(NN + 1) * 4);
    int* deg      = (int*)alloc((size_t)NN * 4);
    int* cursor   = (int*)alloc((size_t)NN * 4);

    hipMemsetAsync(deg, 0, NN * sizeof(int), stream);
    hipMemsetAsync(cursor, 0, NN * sizeof(int), stream);
    // zero A' once per call: agg3 writes only rows<NN, k<800 of each segment;
    // padding must be zero and ws is re-poisoned before every timed call.
    hipMemsetAsync(Ap, 0, (size_t)MPAD * 1664 * 2, stream);

    int eb = (EPE + 255) / 256;
    build_edges_kernel<<<eb, 256, 0, stream>>>(ei, src_all, dst_all, deg);
    scan_kernel<<<1, 1024, 0, stream>>>(deg, row_ptr, NN);
    scatter_kernel<<<eb, 256, 0, stream>>>(src_all, dst_all, row_ptr, cursor, col_src, col_eid);

    // layer 0 A' from X
    {
        size_t na = (size_t)MPAD * 256;
        convA_kernel<<<(int)((na + 255) / 256), 256, 0, stream>>>(X, 200, 200, 256, Ap0);
    }

    for (int i = 0; i < 5; ++i) {
        int Fin = (i == 0) ? 200 : 800;
        int H   = (i == 4) ? 1 : 4;
        int HC  = H * CC;
        int Kp  = (Fin == 200) ? 256 : 832;
        int Kt  = 2 * Kp;
        int Np  = (HC == 800) ? 896 : 256;
        int ncol = Np / 128;
        const unsigned short* Acur = (i == 0) ? Ap0 : Ap;
        const float* W   = (const float*)d_in[2 + 4 * i];
        const float* as_ = (const float*)d_in[3 + 4 * i];
        const float* ad_ = (const float*)d_in[4 + 4 * i];
        const float* b_  = (const float*)d_in[5 + 4 * i];

        size_t nb = (size_t)Np * Kp;
        convB_kernel<<<(int)((nb + 255) / 256), 256, 0, stream>>>(W, Fin, HC, Kp, Np, Bp);

        gemm_mfma<<<ncol * (MPAD / 128), 256, 0, stream>>>(Acur, Bp, hbuf, Kt, Np, ncol);

        attn_kernel<<<NN, 256, 0, stream>>>(hbuf, as_, ad_, asrc, adst, H, Np);

        mden_kernel<<<(NN * H + 255) / 256, 256, 0, stream>>>(asrc, adst, row_ptr, col_src,
                                                              m_arr, den_arr, H);

        float* wptr = (i == 4) ? (float*)d_out + (size_t)NN * CC : wbuf;
        weight_kernel<<<(EPE * H + 255) / 256, 256, 0, stream>>>(src_all, dst_all, asrc, adst,
                                                                 m_arr, den_arr, wptr, H);

        float* out32 = (i == 4) ? (float*)d_out : nullptr;
        unsigned short* apn = (i == 4) ? nullptr : Ap;
        agg3_kernel<<<NN, 256, 0, stream>>>(hbuf, wptr, row_ptr, col_src, col_eid, b_,
                                            out32, apn, H, HC, Np);
    }
}

// Round 5
// 562.611 us; speedup vs baseline: 3.9893x; 1.1436x over previous
//
#include <hip/hip_runtime.h>
#include <math.h>

#define NN 10000
#define EE 100000
#define EPE 110000   // edges + self loops
#define CC 200
#define MPAD 10112   // 79 * 128

typedef __attribute__((ext_vector_type(8))) _Float16 f16x8;
typedef __attribute__((ext_vector_type(4))) _Float16 f16x4;
typedef __attribute__((ext_vector_type(4))) unsigned short u16x4;
typedef __attribute__((ext_vector_type(4))) float f32x4;

__device__ __forceinline__ float lrelu(float v) { return v >= 0.f ? v : 0.2f * v; }
__device__ __forceinline__ float gelu_f(float v) { return 0.5f * v * (1.f + erff(v * 0.70710678118654752f)); }

// ---------------- CSR build ----------------

__global__ void build_edges_kernel(const int* __restrict__ ei,
                                   int* __restrict__ src_all, int* __restrict__ dst_all,
                                   int* __restrict__ deg) {
    int e = blockIdx.x * blockDim.x + threadIdx.x;
    if (e >= EPE) return;
    int s, d;
    if (e < EE) { s = ei[e]; d = ei[EE + e]; }
    else        { s = e - EE; d = e - EE; }
    src_all[e] = s;
    dst_all[e] = d;
    atomicAdd(&deg[d], 1);
}

__global__ void scan_kernel(const int* __restrict__ deg, int* __restrict__ row_ptr, int n) {
    __shared__ int wsum[16];
    int tid = threadIdx.x;
    int lane = tid & 63, w = tid >> 6;
    int carry = 0;
    for (int base = 0; base < n; base += 1024) {
        int idx = base + tid;
        int v = (idx < n) ? deg[idx] : 0;
        int x = v;
#pragma unroll
        for (int off = 1; off < 64; off <<= 1) {
            int t = __shfl_up(x, off);
            if (lane >= off) x += t;
        }
        if (lane == 63) wsum[w] = x;
        __syncthreads();
        if (w == 0) {
            int s = (lane < 16) ? wsum[lane] : 0;
#pragma unroll
            for (int off = 1; off < 16; off <<= 1) {
                int t = __shfl_up(s, off);
                if (lane >= off) s += t;
            }
            if (lane < 16) wsum[lane] = s;
        }
        __syncthreads();
        int woff = (w > 0) ? wsum[w - 1] : 0;
        if (idx < n) row_ptr[idx] = carry + woff + x - v;   // exclusive
        carry += wsum[15];
        __syncthreads();
    }
    if (tid == 0) row_ptr[n] = carry;
}

__global__ void scatter_kernel(const int* __restrict__ src_all, const int* __restrict__ dst_all,
                               const int* __restrict__ row_ptr, int* __restrict__ cursor,
                               int* __restrict__ col_src, int* __restrict__ col_eid) {
    int e = blockIdx.x * blockDim.x + threadIdx.x;
    if (e >= EPE) return;
    int d = dst_all[e];
    int pos = row_ptr[d] + atomicAdd(&cursor[d], 1);
    col_src[pos] = src_all[e];
    col_eid[pos] = e;
}

// ---------------- fp16 conversion (single segment) ----------------

__global__ void convA_kernel(const float* __restrict__ x, int sx, int Fin, int Kp,
                             unsigned short* __restrict__ Ap) {
    size_t idx = (size_t)blockIdx.x * 256 + threadIdx.x;
    if (idx >= (size_t)MPAD * Kp) return;
    int row = (int)(idx / Kp);
    int kk  = (int)(idx % Kp);
    float v = 0.f;
    if (row < NN && kk < Fin) v = x[(size_t)row * sx + kk];
    Ap[idx] = __builtin_bit_cast(unsigned short, (_Float16)v);
}

// B' transposed to [n][k]
__global__ void convB_kernel(const float* __restrict__ W, int Fin, int HC, int Kp, int Np,
                             unsigned short* __restrict__ Bp) {
    size_t idx = (size_t)blockIdx.x * 256 + threadIdx.x;
    if (idx >= (size_t)Np * Kp) return;
    int n  = (int)(idx / Kp);
    int kk = (int)(idx % Kp);
    float v = 0.f;
    if (n < HC && kk < Fin) v = W[(size_t)kk * HC + n];
    Bp[idx] = __builtin_bit_cast(unsigned short, (_Float16)v);
}

// ---------------- MFMA GEMM: C[MPAD x Np](fp16) = A[MPAD x Kt] * B[Np x Kt]^T ----------------
// 128x128 tile, BK=64, 4 waves, 16x16x32 f16 MFMA, global_load_lds w16,
// XOR chunk swizzle via pre-swizzled source, XCD-bijective block swizzle,
// 2-phase LDS double-buffer with counted vmcnt(8) (next tile stays in flight).

__global__ __launch_bounds__(256) void gemm_mfma(const unsigned short* __restrict__ A,
                                                 const unsigned short* __restrict__ B,
                                                 unsigned short* __restrict__ C,
                                                 int Kt, int Np, int ncol) {
    __shared__ unsigned short As[2][8192];   // 2 x 16 KB
    __shared__ unsigned short Bs[2][8192];

    int tid = threadIdx.x;
    int lane = tid & 63, wave = tid >> 6;

    int nwg = gridDim.x;
    int orig = blockIdx.x;
    int q = nwg >> 3, r = nwg & 7;
    int xcd = orig & 7, sidx = orig >> 3;
    int wg = (xcd < r ? xcd * (q + 1) : r * (q + 1) + (xcd - r) * q) + sidx;
    int rowT = wg / ncol, colT = wg - rowT * ncol;
    int row0 = rowT * 128, col0 = colT * 128;
    int wr = wave >> 1, wc = wave & 1;

    size_t gAoff[4], gBoff[4];
    int ldsSeg[4];
#pragma unroll
    for (int i = 0; i < 4; ++i) {
        int seg = wave * 4 + i;            // 0..15
        int chunkIdx = seg * 64 + lane;    // 0..1023
        int rr = chunkIdx >> 3;            // row 0..127
        int c = chunkIdx & 7;
        int cg = c ^ (rr & 7);             // pre-swizzled source chunk
        gAoff[i] = (size_t)(row0 + rr) * Kt + (size_t)cg * 8;
        gBoff[i] = (size_t)(col0 + rr) * Kt + (size_t)cg * 8;
        ldsSeg[i] = seg * 512;
    }

    int rowA[4], rowB[4];
#pragma unroll
    for (int m = 0; m < 4; ++m) {
        rowA[m] = wr * 64 + m * 16 + (lane & 15);
        rowB[m] = wc * 64 + m * 16 + (lane & 15);
    }

    f32x4 acc[4][4];
#pragma unroll
    for (int m = 0; m < 4; ++m)
#pragma unroll
        for (int n = 0; n < 4; ++n) acc[m][n] = f32x4{0.f, 0.f, 0.f, 0.f};

#define STAGE(bufi, kk)                                                                     \
    _Pragma("unroll")                                                                       \
    for (int i = 0; i < 4; ++i) {                                                           \
        __builtin_amdgcn_global_load_lds(                                                   \
            (const __attribute__((address_space(1))) void*)(A + gAoff[i] + (kk)),           \
            (__attribute__((address_space(3))) void*)(&As[bufi][ldsSeg[i]]), 16, 0, 0);     \
        __builtin_amdgcn_global_load_lds(                                                   \
            (const __attribute__((address_space(1))) void*)(B + gBoff[i] + (kk)),           \
            (__attribute__((address_space(3))) void*)(&Bs[bufi][ldsSeg[i]]), 16, 0, 0);     \
    }

    int nk = Kt >> 6;
    STAGE(0, 0)

    for (int t = 0; t < nk; ++t) {
        int cur = t & 1;
        if (t + 1 < nk) {
            STAGE(1 - cur, (t + 1) * 64)
            asm volatile("s_waitcnt vmcnt(8)" ::: "memory");   // current tile's 8 loads done
        } else {
            asm volatile("s_waitcnt vmcnt(0)" ::: "memory");
        }
        __builtin_amdgcn_s_barrier();
        __builtin_amdgcn_sched_barrier(0);

        const unsigned short* asb = As[cur];
        const unsigned short* bsb = Bs[cur];
#pragma unroll
        for (int kh = 0; kh < 2; ++kh) {
            int cw = kh * 4 + (lane >> 4);
            f16x8 a[4], b[4];
#pragma unroll
            for (int m = 0; m < 4; ++m) {
                int ia = rowA[m] * 64 + ((cw ^ (rowA[m] & 7)) << 3);
                a[m] = *(const f16x8*)(&asb[ia]);
            }
#pragma unroll
            for (int n = 0; n < 4; ++n) {
                int ib = rowB[n] * 64 + ((cw ^ (rowB[n] & 7)) << 3);
                b[n] = *(const f16x8*)(&bsb[ib]);
            }
            if (kh == 0) __builtin_amdgcn_s_setprio(1);
#pragma unroll
            for (int m = 0; m < 4; ++m)
#pragma unroll
                for (int n = 0; n < 4; ++n)
                    acc[m][n] = __builtin_amdgcn_mfma_f32_16x16x32_f16(a[m], b[n], acc[m][n], 0, 0, 0);
        }
        __builtin_amdgcn_s_setprio(0);
        asm volatile("s_waitcnt lgkmcnt(0)" ::: "memory");     // own LDS reads done
        __builtin_amdgcn_sched_barrier(0);
        __builtin_amdgcn_s_barrier();                          // safe to overwrite buf[cur] next iter
        __builtin_amdgcn_sched_barrier(0);
    }
#undef STAGE

    int crow = row0 + wr * 64 + ((lane >> 4) << 2);
    int ccol = col0 + wc * 64 + (lane & 15);
#pragma unroll
    for (int m = 0; m < 4; ++m)
#pragma unroll
        for (int j = 0; j < 4; ++j) {
            size_t rb = (size_t)(crow + m * 16 + j) * Np;
#pragma unroll
            for (int n = 0; n < 4; ++n)
                C[rb + ccol + n * 16] =
                    __builtin_bit_cast(unsigned short, (_Float16)acc[m][n][j]);
        }
}

// ---------------- attention scores (vectorized fp16 h) ----------------

__global__ void attn_kernel(const unsigned short* __restrict__ h,
                            const float* __restrict__ a_s, const float* __restrict__ a_d,
                            float* __restrict__ asrc, float* __restrict__ adst,
                            int H, int HCp) {
    int n = blockIdx.x;
    int wave = threadIdx.x >> 6;
    int lane = threadIdx.x & 63;
    if (wave >= H) return;
    float sa = 0.f, da = 0.f;
    int c0 = lane * 4;
    if (c0 < CC) {
        f16x4 hv = *(const f16x4*)(h + (size_t)n * HCp + wave * CC + c0);
        float4 av = *(const float4*)(a_s + wave * CC + c0);
        float4 dv = *(const float4*)(a_d + wave * CC + c0);
        float h0 = (float)hv[0], h1 = (float)hv[1], h2 = (float)hv[2], h3 = (float)hv[3];
        sa = h0 * av.x + h1 * av.y + h2 * av.z + h3 * av.w;
        da = h0 * dv.x + h1 * dv.y + h2 * dv.z + h3 * dv.w;
    }
#pragma unroll
    for (int off = 32; off > 0; off >>= 1) {
        sa += __shfl_down(sa, off);
        da += __shfl_down(da, off);
    }
    if (lane == 0) {
        asrc[n * H + wave] = sa;
        adst[n * H + wave] = da;
    }
}

// ---------------- per-(node,head) online softmax m/den ----------------

__global__ void mden_kernel(const float* __restrict__ asrc, const float* __restrict__ adst,
                            const int* __restrict__ row_ptr, const int* __restrict__ col_src,
                            float* __restrict__ m_arr, float* __restrict__ den_arr, int H) {
    int i = blockIdx.x * blockDim.x + threadIdx.x;
    if (i >= NN * H) return;
    int n = i / H, hd = i - n * H;
    float ad = adst[i];
    int beg = row_ptr[n], end = row_ptr[n + 1];
    float m = -1e30f, den = 0.f;
    for (int e = beg; e < end; ++e) {
        int s = col_src[e];
        float v = lrelu(asrc[s * H + hd] + ad);
        if (v > m) { den = den * expf(m - v) + 1.f; m = v; }
        else den += expf(v - m);
    }
    m_arr[i] = m;
    den_arr[i] = den;
}

// ---------------- per-(edge,head) softmax weight, original edge order ----------------

__global__ void weight_kernel(const int* __restrict__ src_all, const int* __restrict__ dst_all,
                              const float* __restrict__ asrc, const float* __restrict__ adst,
                              const float* __restrict__ m_arr, const float* __restrict__ den_arr,
                              float* __restrict__ w, int H) {
    int i = blockIdx.x * blockDim.x + threadIdx.x;
    if (i >= EPE * H) return;
    int e = i / H, hd = i - e * H;
    int s = src_all[e], d = dst_all[e];
    float v = lrelu(asrc[s * H + hd] + adst[d * H + hd]);
    w[i] = expf(v - m_arr[d * H + hd]) / den_arr[d * H + hd];
}

// ---------------- aggregation + bias + gelu; writes next layer's A (fp16) or d_out ----------------

__global__ __launch_bounds__(256) void agg3_kernel(const unsigned short* __restrict__ h,
                                                   const float* __restrict__ w,
                                                   const int* __restrict__ row_ptr,
                                                   const int* __restrict__ col_src,
                                                   const int* __restrict__ col_eid,
                                                   const float* __restrict__ bias,
                                                   float* __restrict__ out32,
                                                   unsigned short* __restrict__ apn,
                                                   int H, int HC, int HCp) {
    int n = blockIdx.x;
    int hc0 = threadIdx.x * 4;
    if (hc0 >= HC) return;
    int head = hc0 / CC;
    int beg = row_ptr[n], end = row_ptr[n + 1];

    float a0 = 0.f, a1 = 0.f, a2 = 0.f, a3 = 0.f;
    // 1-deep prefetch pipeline (T14)
    int s = col_src[beg], eid = col_eid[beg];
    float wv = w[(size_t)eid * H + head];
    f16x4 hv = *(const f16x4*)(h + (size_t)s * HCp + hc0);
    for (int e = beg; e < end; ++e) {
        int s2 = 0, eid2 = 0; float wv2 = 0.f; f16x4 hv2 = {};
        if (e + 1 < end) {
            s2 = col_src[e + 1]; eid2 = col_eid[e + 1];
            wv2 = w[(size_t)eid2 * H + head];
            hv2 = *(const f16x4*)(h + (size_t)s2 * HCp + hc0);
        }
        a0 += wv * (float)hv[0];
        a1 += wv * (float)hv[1];
        a2 += wv * (float)hv[2];
        a3 += wv * (float)hv[3];
        s = s2; eid = eid2; wv = wv2; hv = hv2;
    }
    float4 bv = *(const float4*)(bias + hc0);
    float g0 = gelu_f(a0 + bv.x), g1 = gelu_f(a1 + bv.y);
    float g2 = gelu_f(a2 + bv.z), g3 = gelu_f(a3 + bv.w);
    if (out32) {
        *(float4*)(out32 + (size_t)n * HC + hc0) = float4{g0, g1, g2, g3};
    } else {
        *(u16x4*)(apn + (size_t)n * 832 + hc0) = u16x4{
            __builtin_bit_cast(unsigned short, (_Float16)g0),
            __builtin_bit_cast(unsigned short, (_Float16)g1),
            __builtin_bit_cast(unsigned short, (_Float16)g2),
            __builtin_bit_cast(unsigned short, (_Float16)g3)};
    }
}

// ---------------- host ----------------

extern "C" void kernel_launch(void* const* d_in, const int* in_sizes, int n_in,
                              void* d_out, int out_size, void* d_ws, size_t ws_size,
                              hipStream_t stream) {
    const float* X = (const float*)d_in[0];
    const int* ei = (const int*)d_in[1];

    char* ws = (char*)d_ws;
    size_t off = 0;
    auto alloc = [&](size_t bytes) { void* p = ws + off; off += (bytes + 255) & ~(size_t)255; return p; };

    unsigned short* Ap0 = (unsigned short*)alloc((size_t)MPAD * 256 * 2);   // 5.2 MB
    unsigned short* Ap  = (unsigned short*)alloc((size_t)MPAD * 832 * 2);   // 16.8 MB
    unsigned short* Bp  = (unsigned short*)alloc((size_t)896 * 832 * 2);    // 1.5 MB
    unsigned short* hbuf= (unsigned short*)alloc((size_t)MPAD * 896 * 2);   // 18.1 MB
    float* asrc   = (float*)alloc((size_t)NN * 4 * 4);
    float* adst   = (float*)alloc((size_t)NN * 4 * 4);
    float* m_arr  = (float*)alloc((size_t)NN * 4 * 4);
    float* den_arr= (float*)alloc((size_t)NN * 4 * 4);
    float* wbuf   = (float*)alloc((size_t)EPE * 4 * 4);
    int* src_all  = (int*)alloc((size_t)EPE * 4);
    int* dst_all  = (int*)alloc((size_t)EPE * 4);
    int* col_src  = (int*)alloc((size_t)EPE * 4);
    int* col_eid  = (int*)alloc((size_t)EPE * 4);
    int* row_ptr  = (int*)alloc((size_t)(NN + 1) * 4);
    int* deg      = (int*)alloc((size_t)NN * 4);
    int* cursor   = (int*)alloc((size_t)NN * 4);

    hipMemsetAsync(deg, 0, NN * sizeof(int), stream);
    hipMemsetAsync(cursor, 0, NN * sizeof(int), stream);
    // agg3 writes only rows<NN, cols<800 of Ap; padding must be zero each call
    hipMemsetAsync(Ap, 0, (size_t)MPAD * 832 * 2, stream);

    int eb = (EPE + 255) / 256;
    build_edges_kernel<<<eb, 256, 0, stream>>>(ei, src_all, dst_all, deg);
    scan_kernel<<<1, 1024, 0, stream>>>(deg, row_ptr, NN);
    scatter_kernel<<<eb, 256, 0, stream>>>(src_all, dst_all, row_ptr, cursor, col_src, col_eid);

    // layer 0 A from X (covers all MPAD rows incl. zero padding)
    {
        size_t na = (size_t)MPAD * 256;
        convA_kernel<<<(int)((na + 255) / 256), 256, 0, stream>>>(X, 200, 200, 256, Ap0);
    }

    for (int i = 0; i < 5; ++i) {
        int Fin = (i == 0) ? 200 : 800;
        int H   = (i == 4) ? 1 : 4;
        int HC  = H * CC;
        int Kp  = (Fin == 200) ? 256 : 832;
        int Np  = (HC == 800) ? 896 : 256;
        int ncol = Np / 128;
        const unsigned short* Acur = (i == 0) ? Ap0 : Ap;
        const float* W   = (const float*)d_in[2 + 4 * i];
        const float* as_ = (const float*)d_in[3 + 4 * i];
        const float* ad_ = (const float*)d_in[4 + 4 * i];
        const float* b_  = (const float*)d_in[5 + 4 * i];

        size_t nb = (size_t)Np * Kp;
        convB_kernel<<<(int)((nb + 255) / 256), 256, 0, stream>>>(W, Fin, HC, Kp, Np, Bp);

        gemm_mfma<<<ncol * (MPAD / 128), 256, 0, stream>>>(Acur, Bp, hbuf, Kp, Np, ncol);

        attn_kernel<<<NN, 256, 0, stream>>>(hbuf, as_, ad_, asrc, adst, H, Np);

        mden_kernel<<<(NN * H + 255) / 256, 256, 0, stream>>>(asrc, adst, row_ptr, col_src,
                                                              m_arr, den_arr, H);

        float* wptr = (i == 4) ? (float*)d_out + (size_t)NN * CC : wbuf;
        weight_kernel<<<(EPE * H + 255) / 256, 256, 0, stream>>>(src_all, dst_all, asrc, adst,
                                                                 m_arr, den_arr, wptr, H);

        float* out32 = (i == 4) ? (float*)d_out : nullptr;
        unsigned short* apn = (i == 4) ? nullptr : Ap;
        agg3_kernel<<<NN, 256, 0, stream>>>(hbuf, wptr, row_ptr, col_src, col_eid, b_,
                                            out32, apn, H, HC, Np);
    }
}

// Round 6
// 543.179 us; speedup vs baseline: 4.1320x; 1.0358x over previous
//
#include <hip/hip_runtime.h>
#include <math.h>

#define NN 10000
#define EE 100000
#define EPE 110000   // edges + self loops
#define CC 200
#define MPAD 10112   // 158 * 64

typedef __attribute__((ext_vector_type(8))) _Float16 f16x8;
typedef __attribute__((ext_vector_type(4))) _Float16 f16x4;
typedef __attribute__((ext_vector_type(4))) unsigned short u16x4;
typedef __attribute__((ext_vector_type(4))) float f32x4;

__device__ __forceinline__ float lrelu(float v) { return v >= 0.f ? v : 0.2f * v; }
__device__ __forceinline__ float gelu_f(float v) { return 0.5f * v * (1.f + erff(v * 0.70710678118654752f)); }

// ---------------- CSR build ----------------

__global__ void build_edges_kernel(const int* __restrict__ ei,
                                   int* __restrict__ src_all, int* __restrict__ dst_all,
                                   int* __restrict__ deg) {
    int e = blockIdx.x * blockDim.x + threadIdx.x;
    if (e >= EPE) return;
    int s, d;
    if (e < EE) { s = ei[e]; d = ei[EE + e]; }
    else        { s = e - EE; d = e - EE; }
    src_all[e] = s;
    dst_all[e] = d;
    atomicAdd(&deg[d], 1);
}

__global__ void scan_kernel(const int* __restrict__ deg, int* __restrict__ row_ptr, int n) {
    __shared__ int wsum[16];
    int tid = threadIdx.x;
    int lane = tid & 63, w = tid >> 6;
    int carry = 0;
    for (int base = 0; base < n; base += 1024) {
        int idx = base + tid;
        int v = (idx < n) ? deg[idx] : 0;
        int x = v;
#pragma unroll
        for (int off = 1; off < 64; off <<= 1) {
            int t = __shfl_up(x, off);
            if (lane >= off) x += t;
        }
        if (lane == 63) wsum[w] = x;
        __syncthreads();
        if (w == 0) {
            int s = (lane < 16) ? wsum[lane] : 0;
#pragma unroll
            for (int off = 1; off < 16; off <<= 1) {
                int t = __shfl_up(s, off);
                if (lane >= off) s += t;
            }
            if (lane < 16) wsum[lane] = s;
        }
        __syncthreads();
        int woff = (w > 0) ? wsum[w - 1] : 0;
        if (idx < n) row_ptr[idx] = carry + woff + x - v;   // exclusive
        carry += wsum[15];
        __syncthreads();
    }
    if (tid == 0) row_ptr[n] = carry;
}

__global__ void scatter_kernel(const int* __restrict__ src_all, const int* __restrict__ dst_all,
                               const int* __restrict__ row_ptr, int* __restrict__ cursor,
                               int* __restrict__ col_src, int* __restrict__ col_eid) {
    int e = blockIdx.x * blockDim.x + threadIdx.x;
    if (e >= EPE) return;
    int d = dst_all[e];
    int pos = row_ptr[d] + atomicAdd(&cursor[d], 1);
    col_src[pos] = src_all[e];
    col_eid[pos] = e;
}

// ---------------- fp16 conversion ----------------

__global__ void convA_kernel(const float* __restrict__ x, int sx, int Fin, int Kp,
                             unsigned short* __restrict__ Ap) {
    size_t idx = (size_t)blockIdx.x * 256 + threadIdx.x;
    if (idx >= (size_t)MPAD * Kp) return;
    int row = (int)(idx / Kp);
    int kk  = (int)(idx % Kp);
    float v = 0.f;
    if (row < NN && kk < Fin) v = x[(size_t)row * sx + kk];
    Ap[idx] = __builtin_bit_cast(unsigned short, (_Float16)v);
}

// zero only the pad regions of Ap [MPAD][832] (agg3 writes rows<NN, cols<800)
__global__ void padA_kernel(unsigned short* __restrict__ Ap) {
    int idx = blockIdx.x * 256 + threadIdx.x;
    if (idx < NN * 32) {
        int rw = idx >> 5, c = idx & 31;
        Ap[(size_t)rw * 832 + 800 + c] = 0;
    } else {
        int j = idx - NN * 32;
        if (j < (MPAD - NN) * 832) {
            int rw = j / 832, c = j - rw * 832;
            Ap[(size_t)(NN + rw) * 832 + c] = 0;
        }
    }
}

// B' transposed to [n][k]
__global__ void convB_kernel(const float* __restrict__ W, int Fin, int HC, int Kp, int Np,
                             unsigned short* __restrict__ Bp) {
    size_t idx = (size_t)blockIdx.x * 256 + threadIdx.x;
    if (idx >= (size_t)Np * Kp) return;
    int n  = (int)(idx / Kp);
    int kk = (int)(idx % Kp);
    float v = 0.f;
    if (n < HC && kk < Fin) v = W[(size_t)kk * HC + n];
    Bp[idx] = __builtin_bit_cast(unsigned short, (_Float16)v);
}

// ---------------- MFMA GEMM: C[MPAD x Np](fp16) = A[MPAD x K] * B[Np x K]^T ----------------
// 64x128 tile, BK=64, 4 waves (2x2, per-wave 32x64), 16x16x32 f16 MFMA,
// global_load_lds w16, XOR chunk swizzle via pre-swizzled source,
// XCD-bijective block swizzle, 2-phase dbuf with counted vmcnt(6).

__global__ __launch_bounds__(256) void gemm_mfma(const unsigned short* __restrict__ A,
                                                 const unsigned short* __restrict__ B,
                                                 unsigned short* __restrict__ C,
                                                 int Kt, int Np, int ncol) {
    __shared__ unsigned short As[2][4096];   // 2 x 8 KB  (64 rows x 64 k)
    __shared__ unsigned short Bs[2][8192];   // 2 x 16 KB (128 rows x 64 k)

    int tid = threadIdx.x;
    int lane = tid & 63, wave = tid >> 6;

    int nwg = gridDim.x;
    int orig = blockIdx.x;
    int q = nwg >> 3, r = nwg & 7;
    int xcd = orig & 7, sidx = orig >> 3;
    int wg = (xcd < r ? xcd * (q + 1) : r * (q + 1) + (xcd - r) * q) + sidx;
    int rowT = wg / ncol, colT = wg - rowT * ncol;
    int row0 = rowT * 64, col0 = colT * 128;
    int wr = wave >> 1, wc = wave & 1;

    // A staging: 2 insts/thread, segs 0..7; B staging: 4 insts/thread, segs 0..15
    size_t gAoff[2], gBoff[4];
    int ldsSegA[2], ldsSegB[4];
#pragma unroll
    for (int i = 0; i < 2; ++i) {
        int seg = wave * 2 + i;            // 0..7
        int chunkIdx = seg * 64 + lane;    // 0..511
        int rr = chunkIdx >> 3;            // row 0..63
        int c = chunkIdx & 7;
        int cg = c ^ (rr & 7);
        gAoff[i] = (size_t)(row0 + rr) * Kt + (size_t)cg * 8;
        ldsSegA[i] = seg * 512;
    }
#pragma unroll
    for (int i = 0; i < 4; ++i) {
        int seg = wave * 4 + i;            // 0..15
        int chunkIdx = seg * 64 + lane;    // 0..1023
        int rr = chunkIdx >> 3;            // row 0..127
        int c = chunkIdx & 7;
        int cg = c ^ (rr & 7);
        gBoff[i] = (size_t)(col0 + rr) * Kt + (size_t)cg * 8;
        ldsSegB[i] = seg * 512;
    }

    int rowA[2], rowB[4];
#pragma unroll
    for (int m = 0; m < 2; ++m) rowA[m] = wr * 32 + m * 16 + (lane & 15);
#pragma unroll
    for (int n = 0; n < 4; ++n) rowB[n] = wc * 64 + n * 16 + (lane & 15);

    f32x4 acc[2][4];
#pragma unroll
    for (int m = 0; m < 2; ++m)
#pragma unroll
        for (int n = 0; n < 4; ++n) acc[m][n] = f32x4{0.f, 0.f, 0.f, 0.f};

#define STAGE(bufi, kk)                                                                     \
    _Pragma("unroll")                                                                       \
    for (int i = 0; i < 2; ++i)                                                             \
        __builtin_amdgcn_global_load_lds(                                                   \
            (const __attribute__((address_space(1))) void*)(A + gAoff[i] + (kk)),           \
            (__attribute__((address_space(3))) void*)(&As[bufi][ldsSegA[i]]), 16, 0, 0);    \
    _Pragma("unroll")                                                                       \
    for (int i = 0; i < 4; ++i)                                                             \
        __builtin_amdgcn_global_load_lds(                                                   \
            (const __attribute__((address_space(1))) void*)(B + gBoff[i] + (kk)),           \
            (__attribute__((address_space(3))) void*)(&Bs[bufi][ldsSegB[i]]), 16, 0, 0);

    int nk = Kt >> 6;
    STAGE(0, 0)

    for (int t = 0; t < nk; ++t) {
        int cur = t & 1;
        if (t + 1 < nk) {
            STAGE(1 - cur, (t + 1) * 64)
            asm volatile("s_waitcnt vmcnt(6)" ::: "memory");   // current tile's 6 loads done
        } else {
            asm volatile("s_waitcnt vmcnt(0)" ::: "memory");
        }
        __builtin_amdgcn_s_barrier();
        __builtin_amdgcn_sched_barrier(0);

        const unsigned short* asb = As[cur];
        const unsigned short* bsb = Bs[cur];
#pragma unroll
        for (int kh = 0; kh < 2; ++kh) {
            int cw = kh * 4 + (lane >> 4);
            f16x8 a[2], b[4];
#pragma unroll
            for (int m = 0; m < 2; ++m) {
                int ia = rowA[m] * 64 + ((cw ^ (rowA[m] & 7)) << 3);
                a[m] = *(const f16x8*)(&asb[ia]);
            }
#pragma unroll
            for (int n = 0; n < 4; ++n) {
                int ib = rowB[n] * 64 + ((cw ^ (rowB[n] & 7)) << 3);
                b[n] = *(const f16x8*)(&bsb[ib]);
            }
            if (kh == 0) __builtin_amdgcn_s_setprio(1);
#pragma unroll
            for (int m = 0; m < 2; ++m)
#pragma unroll
                for (int n = 0; n < 4; ++n)
                    acc[m][n] = __builtin_amdgcn_mfma_f32_16x16x32_f16(a[m], b[n], acc[m][n], 0, 0, 0);
        }
        __builtin_amdgcn_s_setprio(0);
        asm volatile("s_waitcnt lgkmcnt(0)" ::: "memory");
        __builtin_amdgcn_sched_barrier(0);
        __builtin_amdgcn_s_barrier();
        __builtin_amdgcn_sched_barrier(0);
    }
#undef STAGE

    int crow = row0 + wr * 32 + ((lane >> 4) << 2);
    int ccol = col0 + wc * 64 + (lane & 15);
#pragma unroll
    for (int m = 0; m < 2; ++m)
#pragma unroll
        for (int j = 0; j < 4; ++j) {
            size_t rb = (size_t)(crow + m * 16 + j) * Np;
#pragma unroll
            for (int n = 0; n < 4; ++n)
                C[rb + ccol + n * 16] =
                    __builtin_bit_cast(unsigned short, (_Float16)acc[m][n][j]);
        }
}

// ---------------- attention scores (vectorized fp16 h) ----------------

__global__ void attn_kernel(const unsigned short* __restrict__ h,
                            const float* __restrict__ a_s, const float* __restrict__ a_d,
                            float* __restrict__ asrc, float* __restrict__ adst,
                            int H, int HCp) {
    int n = blockIdx.x;
    int wave = threadIdx.x >> 6;
    int lane = threadIdx.x & 63;
    if (wave >= H) return;
    float sa = 0.f, da = 0.f;
    int c0 = lane * 4;
    if (c0 < CC) {
        f16x4 hv = *(const f16x4*)(h + (size_t)n * HCp + wave * CC + c0);
        float4 av = *(const float4*)(a_s + wave * CC + c0);
        float4 dv = *(const float4*)(a_d + wave * CC + c0);
        float h0 = (float)hv[0], h1 = (float)hv[1], h2 = (float)hv[2], h3 = (float)hv[3];
        sa = h0 * av.x + h1 * av.y + h2 * av.z + h3 * av.w;
        da = h0 * dv.x + h1 * dv.y + h2 * dv.z + h3 * dv.w;
    }
#pragma unroll
    for (int off = 32; off > 0; off >>= 1) {
        sa += __shfl_down(sa, off);
        da += __shfl_down(da, off);
    }
    if (lane == 0) {
        asrc[n * H + wave] = sa;
        adst[n * H + wave] = da;
    }
}

// ---------------- fused per-(node,head) softmax m/den + per-edge weight ----------------
// writes w[eid*H + head] (original edge order) via col_eid

__global__ void mden_weight_kernel(const float* __restrict__ asrc, const float* __restrict__ adst,
                                   const int* __restrict__ row_ptr, const int* __restrict__ col_src,
                                   const int* __restrict__ col_eid,
                                   float* __restrict__ w, int H) {
    int i = blockIdx.x * blockDim.x + threadIdx.x;
    if (i >= NN * H) return;
    int n = i / H, hd = i - n * H;
    float ad = adst[i];
    int beg = row_ptr[n], end = row_ptr[n + 1];
    float m = -1e30f, den = 0.f;
    for (int e = beg; e < end; ++e) {
        int s = col_src[e];
        float v = lrelu(asrc[s * H + hd] + ad);
        if (v > m) { den = den * expf(m - v) + 1.f; m = v; }
        else den += expf(v - m);
    }
    float inv = 1.f / den;
    for (int e = beg; e < end; ++e) {
        int s = col_src[e];
        float v = lrelu(asrc[s * H + hd] + ad);
        w[(size_t)col_eid[e] * H + hd] = expf(v - m) * inv;
    }
}

// ---------------- aggregation + bias + gelu; writes next layer's A (fp16) or d_out ----------------

__global__ __launch_bounds__(256) void agg3_kernel(const unsigned short* __restrict__ h,
                                                   const float* __restrict__ w,
                                                   const int* __restrict__ row_ptr,
                                                   const int* __restrict__ col_src,
                                                   const int* __restrict__ col_eid,
                                                   const float* __restrict__ bias,
                                                   float* __restrict__ out32,
                                                   unsigned short* __restrict__ apn,
                                                   int H, int HC, int HCp) {
    int n = blockIdx.x;
    int hc0 = threadIdx.x * 4;
    if (hc0 >= HC) return;
    int head = hc0 / CC;
    int beg = row_ptr[n], end = row_ptr[n + 1];

    float a0 = 0.f, a1 = 0.f, a2 = 0.f, a3 = 0.f;
    int s = col_src[beg], eid = col_eid[beg];
    float wv = w[(size_t)eid * H + head];
    f16x4 hv = *(const f16x4*)(h + (size_t)s * HCp + hc0);
    for (int e = beg; e < end; ++e) {
        int s2 = 0, eid2 = 0; float wv2 = 0.f; f16x4 hv2 = {};
        if (e + 1 < end) {
            s2 = col_src[e + 1]; eid2 = col_eid[e + 1];
            wv2 = w[(size_t)eid2 * H + head];
            hv2 = *(const f16x4*)(h + (size_t)s2 * HCp + hc0);
        }
        a0 += wv * (float)hv[0];
        a1 += wv * (float)hv[1];
        a2 += wv * (float)hv[2];
        a3 += wv * (float)hv[3];
        s = s2; eid = eid2; wv = wv2; hv = hv2;
    }
    float4 bv = *(const float4*)(bias + hc0);
    float g0 = gelu_f(a0 + bv.x), g1 = gelu_f(a1 + bv.y);
    float g2 = gelu_f(a2 + bv.z), g3 = gelu_f(a3 + bv.w);
    if (out32) {
        *(float4*)(out32 + (size_t)n * HC + hc0) = float4{g0, g1, g2, g3};
    } else {
        *(u16x4*)(apn + (size_t)n * 832 + hc0) = u16x4{
            __builtin_bit_cast(unsigned short, (_Float16)g0),
            __builtin_bit_cast(unsigned short, (_Float16)g1),
            __builtin_bit_cast(unsigned short, (_Float16)g2),
            __builtin_bit_cast(unsigned short, (_Float16)g3)};
    }
}

// ---------------- host ----------------

extern "C" void kernel_launch(void* const* d_in, const int* in_sizes, int n_in,
                              void* d_out, int out_size, void* d_ws, size_t ws_size,
                              hipStream_t stream) {
    const float* X = (const float*)d_in[0];
    const int* ei = (const int*)d_in[1];

    char* ws = (char*)d_ws;
    size_t off = 0;
    auto alloc = [&](size_t bytes) { void* p = ws + off; off += (bytes + 255) & ~(size_t)255; return p; };

    unsigned short* Ap0 = (unsigned short*)alloc((size_t)MPAD * 256 * 2);   // 5.2 MB
    unsigned short* Ap  = (unsigned short*)alloc((size_t)MPAD * 832 * 2);   // 16.8 MB
    unsigned short* Bp  = (unsigned short*)alloc((size_t)896 * 832 * 2);    // 1.5 MB
    unsigned short* hbuf= (unsigned short*)alloc((size_t)MPAD * 896 * 2);   // 18.1 MB
    float* asrc   = (float*)alloc((size_t)NN * 4 * 4);
    float* adst   = (float*)alloc((size_t)NN * 4 * 4);
    float* wbuf   = (float*)alloc((size_t)EPE * 4 * 4);
    int* src_all  = (int*)alloc((size_t)EPE * 4);
    int* dst_all  = (int*)alloc((size_t)EPE * 4);
    int* col_src  = (int*)alloc((size_t)EPE * 4);
    int* col_eid  = (int*)alloc((size_t)EPE * 4);
    int* row_ptr  = (int*)alloc((size_t)(NN + 1) * 4);
    int* degcur   = (int*)alloc((size_t)2 * NN * 4);
    int* deg = degcur, * cursor = degcur + NN;

    hipMemsetAsync(degcur, 0, 2 * NN * sizeof(int), stream);

    int eb = (EPE + 255) / 256;
    build_edges_kernel<<<eb, 256, 0, stream>>>(ei, src_all, dst_all, deg);
    scan_kernel<<<1, 1024, 0, stream>>>(deg, row_ptr, NN);
    scatter_kernel<<<eb, 256, 0, stream>>>(src_all, dst_all, row_ptr, cursor, col_src, col_eid);

    // zero Ap pad regions (NN*32 + 112*832 elements)
    {
        int npad = NN * 32 + (MPAD - NN) * 832;
        padA_kernel<<<(npad + 255) / 256, 256, 0, stream>>>(Ap);
    }
    // layer 0 A from X (covers all MPAD rows incl. zero padding)
    {
        size_t na = (size_t)MPAD * 256;
        convA_kernel<<<(int)((na + 255) / 256), 256, 0, stream>>>(X, 200, 200, 256, Ap0);
    }

    for (int i = 0; i < 5; ++i) {
        int Fin = (i == 0) ? 200 : 800;
        int H   = (i == 4) ? 1 : 4;
        int HC  = H * CC;
        int Kp  = (Fin == 200) ? 256 : 832;
        int Np  = (HC == 800) ? 896 : 256;
        int ncol = Np / 128;
        const unsigned short* Acur = (i == 0) ? Ap0 : Ap;
        const float* W   = (const float*)d_in[2 + 4 * i];
        const float* as_ = (const float*)d_in[3 + 4 * i];
        const float* ad_ = (const float*)d_in[4 + 4 * i];
        const float* b_  = (const float*)d_in[5 + 4 * i];

        size_t nb = (size_t)Np * Kp;
        convB_kernel<<<(int)((nb + 255) / 256), 256, 0, stream>>>(W, Fin, HC, Kp, Np, Bp);

        gemm_mfma<<<ncol * (MPAD / 64), 256, 0, stream>>>(Acur, Bp, hbuf, Kp, Np, ncol);

        attn_kernel<<<NN, 256, 0, stream>>>(hbuf, as_, ad_, asrc, adst, H, Np);

        float* wptr = (i == 4) ? (float*)d_out + (size_t)NN * CC : wbuf;
        mden_weight_kernel<<<(NN * H + 255) / 256, 256, 0, stream>>>(asrc, adst, row_ptr,
                                                                     col_src, col_eid, wptr, H);

        float* out32 = (i == 4) ? (float*)d_out : nullptr;
        unsigned short* apn = (i == 4) ? nullptr : Ap;
        agg3_kernel<<<NN, 256, 0, stream>>>(hbuf, wptr, row_ptr, col_src, col_eid, b_,
                                            out32, apn, H, HC, Np);
    }
}